// Round 2
// baseline (624.291 us; speedup 1.0000x reference)
//
#include <hip/hip_runtime.h>
#include <cstdint>

#define DIMN 1024
#define SEQ  2048
#define BATCH 2
#define MTOT (BATCH*SEQ)      // 4096 rows
#define NELEM_ACT (MTOT*DIMN) // 4,194,304
#define NELEM_W   (DIMN*DIMN) // 1,048,576

typedef __attribute__((ext_vector_type(8))) short   s16x8;
typedef __attribute__((ext_vector_type(4))) float   f32x4v;

__device__ __forceinline__ float b2f(unsigned short u) {
  union { unsigned int i; float f; } x; x.i = ((unsigned int)u) << 16; return x.f;
}
__device__ __forceinline__ unsigned short f2b(float f) {
  unsigned int x = __float_as_uint(f);
  return (unsigned short)((x + 0x7fffu + ((x >> 16) & 1u)) >> 16);
}

__device__ __forceinline__ void gload16(const void* g, void* l) {
  __builtin_amdgcn_global_load_lds((const __attribute__((address_space(1))) void*)g,
                                   (__attribute__((address_space(3))) void*)l,
                                   16, 0, 0);
}

// ---------------------------------------------------------------------------
// fp32 -> bf16 hi/lo split (elementwise, float4-vectorized)
// ---------------------------------------------------------------------------
__global__ __launch_bounds__(256) void split_cvt_kernel(
    const float* __restrict__ in, unsigned short* __restrict__ hi,
    unsigned short* __restrict__ lo, int n) {
  int i = (blockIdx.x * 256 + threadIdx.x) * 4;
  if (i >= n) return;
  float4 v = *(const float4*)(in + i);
  unsigned short h0 = f2b(v.x), h1 = f2b(v.y), h2 = f2b(v.z), h3 = f2b(v.w);
  ushort4 hv; hv.x = h0; hv.y = h1; hv.z = h2; hv.w = h3;
  *(ushort4*)(hi + i) = hv;
  ushort4 lv;
  lv.x = f2b(v.x - b2f(h0)); lv.y = f2b(v.y - b2f(h1));
  lv.z = f2b(v.z - b2f(h2)); lv.w = f2b(v.w - b2f(h3));
  *(ushort4*)(lo + i) = lv;
}

// ---------------------------------------------------------------------------
// All 5 weight transposes in one dispatch; z selects the weight.
// z=0 -> w1 (hi+lo), z=1 -> w2 (hi+lo), z=2..4 -> q/k/v into combined wqkvt.
// ---------------------------------------------------------------------------
__global__ __launch_bounds__(256) void transpose5_kernel(
    const float* __restrict__ w1, const float* __restrict__ w2,
    const float* __restrict__ qw, const float* __restrict__ kw,
    const float* __restrict__ vw,
    unsigned short* __restrict__ w1thi, unsigned short* __restrict__ w1tlo,
    unsigned short* __restrict__ w2thi, unsigned short* __restrict__ w2tlo,
    unsigned short* __restrict__ wqkvt) {
  __shared__ float t[32][33];
  int z = blockIdx.z;
  const float* in = (z == 0) ? w1 : (z == 1) ? w2 : (z == 2) ? qw : (z == 3) ? kw : vw;
  unsigned short* hi = (z == 0) ? w1thi : (z == 1) ? w2thi : wqkvt + (size_t)(z - 2) * NELEM_W;
  unsigned short* lo = (z == 0) ? w1tlo : (z == 1) ? w2tlo : nullptr;

  int tx = threadIdx.x & 31, ty = threadIdx.x >> 5;  // 32 x 8
  int r0 = blockIdx.y * 32, c0 = blockIdx.x * 32;
  #pragma unroll
  for (int i = 0; i < 32; i += 8)
    t[ty + i][tx] = in[(size_t)(r0 + ty + i) * DIMN + c0 + tx];
  __syncthreads();
  #pragma unroll
  for (int i = 0; i < 32; i += 8) {
    float v = t[tx][ty + i];
    size_t off = (size_t)(c0 + ty + i) * DIMN + r0 + tx;
    unsigned short h = f2b(v);
    hi[off] = h;
    if (lo) lo[off] = f2b(v - b2f(h));
  }
}

// ---------------------------------------------------------------------------
// GEMM: C[M,N] = A[M,K] @ Bt[N,K]^T + bias
// 128x128 tile, BK=32, 256 threads (4 waves, 2x2; each wave 64x64 = 4x4 frags)
// Double-buffered LDS staging: issue global_load_lds for tile t+1 BEFORE
// computing tile t; single __syncthreads per K-step (= vmcnt0+lgkmcnt0+bar).
// Fragment-major LDS: each 16x32 fragment block is 1KB, lane-contiguous ->
// both global_load_lds(16B) and ds_read_b128 conflict-free by construction.
// SPLIT: 3-term split-bf16 product (~fp32 accuracy).
// EPI 0: relu, write hi/lo bf16.  EPI 1: bf16 + bias0.  EPI 2: bf16, bias
// selected per 1024-col group (fused QKV).
// ---------------------------------------------------------------------------
template<bool SPLIT, int EPI>
__global__ __launch_bounds__(256) void gemm_kernel(
    const unsigned short* __restrict__ A,  const unsigned short* __restrict__ Alo,
    const unsigned short* __restrict__ Bt, const unsigned short* __restrict__ Btlo,
    const float* __restrict__ bias0, const float* __restrict__ bias1,
    const float* __restrict__ bias2,
    unsigned short* __restrict__ O, unsigned short* __restrict__ Olo,
    int Ndim, int Kdim) {
  constexpr int NB = SPLIT ? 32 : 16;          // 1KB fragment blocks per buffer
  __shared__ unsigned short lds[2 * NB * 512];

  const int tid  = threadIdx.x;
  const int lane = tid & 63;
  const int wave = tid >> 6;
  const int wm = wave >> 1;
  const int wn = wave & 1;
  const int frow = lane & 15;
  const int krow = lane >> 4;
  const int bm0 = blockIdx.y * 128;
  const int bn0 = blockIdx.x * 128;

  f32x4v acc[4][4] = {};
  const int nt = Kdim >> 5;

  auto stage = [&](int buf, int k0) {
    unsigned short* dst = lds + (size_t)buf * (NB * 512);
    #pragma unroll
    for (int t = 0; t < NB / 4; ++t) {
      int i = wave + t * 4;
      int ii = i & 15;
      const unsigned short* src = (i < 16) ? (ii < 8 ? A : Bt)
                                           : (ii < 8 ? Alo : Btlo);
      int row = (ii < 8) ? (bm0 + ii * 16 + frow)
                         : (bn0 + (ii - 8) * 16 + frow);
      gload16(src + (size_t)row * Kdim + k0 + krow * 8, dst + i * 512);
    }
  };

  stage(0, 0);
  __syncthreads();
  int cur = 0;
  for (int t = 0; t < nt; ++t) {
    if (t + 1 < nt) stage(cur ^ 1, (t + 1) * 32);   // prefetch next tile

    const short* sl = (const short*)(lds + (size_t)cur * (NB * 512));
    s16x8 a[4], b[4];
    #pragma unroll
    for (int m = 0; m < 4; ++m)
      a[m] = *(const s16x8*)(sl + (wm * 4 + m) * 512 + lane * 8);
    #pragma unroll
    for (int n = 0; n < 4; ++n)
      b[n] = *(const s16x8*)(sl + (8 + wn * 4 + n) * 512 + lane * 8);

    if constexpr (SPLIT) {
      s16x8 al[4], bl[4];
      #pragma unroll
      for (int m = 0; m < 4; ++m)
        al[m] = *(const s16x8*)(sl + (16 + wm * 4 + m) * 512 + lane * 8);
      #pragma unroll
      for (int n = 0; n < 4; ++n)
        bl[n] = *(const s16x8*)(sl + (24 + wn * 4 + n) * 512 + lane * 8);
      #pragma unroll
      for (int m = 0; m < 4; ++m)
        #pragma unroll
        for (int n = 0; n < 4; ++n) {
          acc[m][n] = __builtin_amdgcn_mfma_f32_16x16x32_bf16(a[m],  b[n],  acc[m][n], 0, 0, 0);
          acc[m][n] = __builtin_amdgcn_mfma_f32_16x16x32_bf16(a[m],  bl[n], acc[m][n], 0, 0, 0);
          acc[m][n] = __builtin_amdgcn_mfma_f32_16x16x32_bf16(al[m], b[n],  acc[m][n], 0, 0, 0);
        }
    } else {
      #pragma unroll
      for (int m = 0; m < 4; ++m)
        #pragma unroll
        for (int n = 0; n < 4; ++n)
          acc[m][n] = __builtin_amdgcn_mfma_f32_16x16x32_bf16(a[m], b[n], acc[m][n], 0, 0, 0);
    }
    __syncthreads();   // stage(t+1) complete + all waves done reading buf cur
    cur ^= 1;
  }

  // epilogue: C row = (lane>>4)*4 + r, col = lane&15 within each 16x16 frag
  #pragma unroll
  for (int n = 0; n < 4; ++n) {
    int col = bn0 + wn * 64 + n * 16 + frow;
    float bv;
    if (EPI == 2) {
      int sel = col >> 10;
      const float* bp = (sel == 0) ? bias0 : (sel == 1) ? bias1 : bias2;
      bv = bp[col & (DIMN - 1)];
    } else {
      bv = bias0[col];
    }
    #pragma unroll
    for (int m = 0; m < 4; ++m) {
      int rbase = bm0 + wm * 64 + m * 16 + krow * 4;
      #pragma unroll
      for (int r = 0; r < 4; ++r) {
        float v = acc[m][n][r] + bv;
        size_t off = (size_t)(rbase + r) * Ndim + col;
        if (EPI == 0) {
          v = fmaxf(v, 0.f);
          unsigned short h = f2b(v);
          O[off] = h;
          Olo[off] = f2b(v - b2f(h));
        } else {
          O[off] = f2b(v);
        }
      }
    }
  }
}

// ---------------------------------------------------------------------------
// Sliding-window attention on fused QKV buffer [M][3072] (q|k|v).
// One block per (b,s). q in registers; PV split 4x across waves with a
// bank-clean [wave][i][lane] partial layout (max 2-way = free).
// ---------------------------------------------------------------------------
__global__ __launch_bounds__(256) void attn_kernel(
    const unsigned short* __restrict__ qkv, float* __restrict__ out) {
  __shared__ float sc[72];
  __shared__ float wts[72];
  __shared__ float part[4][16][68];
  const float NEG_INF = -__builtin_huge_valf();
  const int ROWS = 3 * DIMN;

  int bs = blockIdx.x;
  int s = bs & (SEQ - 1);
  int tid = threadIdx.x, lane = tid & 63, wave = tid >> 6;

  // q slice (16 dims per lane) into registers, pre-scaled by 1/sqrt(1024)
  float qr[16];
  {
    const unsigned short* qp = qkv + (size_t)bs * ROWS + lane * 16;
    s16x8 q0 = *(const s16x8*)qp;
    s16x8 q1 = *(const s16x8*)(qp + 8);
    #pragma unroll
    for (int i = 0; i < 8; ++i) {
      qr[i]     = b2f((unsigned short)q0[i]) * 0.03125f;
      qr[8 + i] = b2f((unsigned short)q1[i]) * 0.03125f;
    }
  }

  const unsigned short* kbase = qkv + (size_t)(bs - s) * ROWS + DIMN;
  for (int j = wave; j < 65; j += 4) {
    int pos = s - 32 + j;
    float dot;
    if (pos >= 0 && pos < SEQ) {
      const unsigned short* kp = kbase + (size_t)pos * ROWS + lane * 16;
      s16x8 k0 = *(const s16x8*)kp;
      s16x8 k1 = *(const s16x8*)(kp + 8);
      dot = 0.f;
      #pragma unroll
      for (int i = 0; i < 8; ++i)
        dot += qr[i] * b2f((unsigned short)k0[i]) + qr[8 + i] * b2f((unsigned short)k1[i]);
      #pragma unroll
      for (int off = 32; off > 0; off >>= 1) dot += __shfl_xor(dot, off);
    } else {
      dot = NEG_INF;
    }
    if (lane == 0) sc[j] = dot;
  }
  __syncthreads();

  if (wave == 0) {
    float v0 = sc[lane];
    float v1 = (lane == 0) ? sc[64] : NEG_INF;
    float mx = fmaxf(v0, v1);
    #pragma unroll
    for (int off = 32; off > 0; off >>= 1) mx = fmaxf(mx, __shfl_xor(mx, off));
    float p0 = __expf(v0 - mx);
    float p1 = (lane == 0) ? __expf(v1 - mx) : 0.f;
    float sm = p0 + p1;
    #pragma unroll
    for (int off = 32; off > 0; off >>= 1) sm += __shfl_xor(sm, off);
    float inv = 1.f / sm;
    wts[lane] = p0 * inv;
    if (lane == 0) wts[64] = p1 * inv;
  }
  __syncthreads();

  // PV: wave w handles j = w, w+4, ...; lane covers dims lane*16..+15
  float acc[16];
  #pragma unroll
  for (int i = 0; i < 16; ++i) acc[i] = 0.f;
  const unsigned short* vbase = qkv + (size_t)(bs - s) * ROWS + 2 * DIMN;
  for (int j = wave; j < 65; j += 4) {
    int pos = s - 32 + j;
    if (pos < 0 || pos >= SEQ) continue;
    float w = wts[j];
    const unsigned short* vp = vbase + (size_t)pos * ROWS + lane * 16;
    s16x8 v0 = *(const s16x8*)vp;
    s16x8 v1 = *(const s16x8*)(vp + 8);
    #pragma unroll
    for (int i = 0; i < 8; ++i) {
      acc[i]     += w * b2f((unsigned short)v0[i]);
      acc[8 + i] += w * b2f((unsigned short)v1[i]);
    }
  }
  #pragma unroll
  for (int i = 0; i < 16; ++i) part[wave][i][lane] = acc[i];
  __syncthreads();

  // reduce 4 partials; thread handles dims d0..d0+3
  int d0 = tid * 4;
  int lsrc = d0 >> 4;
  int ibase = d0 & 15;
  float r0 = 0.f, r1 = 0.f, r2 = 0.f, r3 = 0.f;
  #pragma unroll
  for (int w = 0; w < 4; ++w) {
    r0 += part[w][ibase + 0][lsrc];
    r1 += part[w][ibase + 1][lsrc];
    r2 += part[w][ibase + 2][lsrc];
    r3 += part[w][ibase + 3][lsrc];
  }
  float4 r; r.x = r0; r.y = r1; r.z = r2; r.w = r3;
  *(float4*)(out + (size_t)bs * DIMN + d0) = r;
}

// ---------------------------------------------------------------------------
extern "C" void kernel_launch(void* const* d_in, const int* in_sizes, int n_in,
                              void* d_out, int out_size, void* d_ws, size_t ws_size,
                              hipStream_t stream) {
  const float* x  = (const float*)d_in[0];
  const float* w1 = (const float*)d_in[1];
  const float* b1 = (const float*)d_in[2];
  const float* w2 = (const float*)d_in[3];
  const float* b2 = (const float*)d_in[4];
  const float* qw = (const float*)d_in[5];
  const float* qb = (const float*)d_in[6];
  const float* kw = (const float*)d_in[7];
  const float* kb = (const float*)d_in[8];
  const float* vw = (const float*)d_in[9];
  const float* vb = (const float*)d_in[10];
  float* out = (float*)d_out;

  char* ws = (char*)d_ws;
  const size_t SA = (size_t)NELEM_ACT * 2;   // 8 MB
  const size_t SW = (size_t)NELEM_W * 2;     // 2 MB
  unsigned short* xhi   = (unsigned short*)(ws);
  unsigned short* xlo   = (unsigned short*)(ws + SA);
  unsigned short* h_hi  = (unsigned short*)(ws + 2*SA);
  unsigned short* h_lo  = (unsigned short*)(ws + 3*SA);
  unsigned short* m_bf  = (unsigned short*)(ws + 4*SA);
  unsigned short* w1thi = (unsigned short*)(ws + 5*SA);
  unsigned short* w1tlo = (unsigned short*)(ws + 5*SA + SW);
  unsigned short* w2thi = (unsigned short*)(ws + 5*SA + 2*SW);
  unsigned short* w2tlo = (unsigned short*)(ws + 5*SA + 3*SW);
  unsigned short* wqkvt = (unsigned short*)(ws + 5*SA + 4*SW);  // [3072][1024]
  // qkv output [4096][3072] overlays dead xhi/xlo/h_hi (3*SA = 24 MB)
  unsigned short* qkv   = xhi;

  split_cvt_kernel<<<NELEM_ACT / (256 * 4), 256, 0, stream>>>(x, xhi, xlo, NELEM_ACT);
  transpose5_kernel<<<dim3(32, 32, 5), 256, 0, stream>>>(w1, w2, qw, kw, vw,
                                                         w1thi, w1tlo, w2thi, w2tlo, wqkvt);

  dim3 g1(DIMN / 128, MTOT / 128);     // (8, 32)
  gemm_kernel<true, 0><<<g1, 256, 0, stream>>>(xhi, xlo, w1thi, w1tlo,
                                               b1, nullptr, nullptr,
                                               h_hi, h_lo, DIMN, DIMN);
  gemm_kernel<true, 1><<<g1, 256, 0, stream>>>(h_hi, h_lo, w2thi, w2tlo,
                                               b2, nullptr, nullptr,
                                               m_bf, nullptr, DIMN, DIMN);
  dim3 g2(3 * DIMN / 128, MTOT / 128); // (24, 32)
  gemm_kernel<false, 2><<<g2, 256, 0, stream>>>(m_bf, nullptr, wqkvt, nullptr,
                                                qb, kb, vb,
                                                qkv, nullptr, 3 * DIMN, DIMN);

  attn_kernel<<<MTOT, 256, 0, stream>>>(qkv, out);
}

// Round 3
// 272.432 us; speedup vs baseline: 2.2915x; 2.2915x over previous
//
#include <hip/hip_runtime.h>
#include <cstdint>

#define DIMN 1024
#define SEQ  2048
#define BATCH 2
#define MTOT (BATCH*SEQ)      // 4096 rows
#define NELEM_ACT (MTOT*DIMN) // 4,194,304
#define NELEM_W   (DIMN*DIMN) // 1,048,576

typedef __attribute__((ext_vector_type(8))) short   s16x8;
typedef __attribute__((ext_vector_type(4))) float   f32x4v;

__device__ __forceinline__ float b2f(unsigned short u) {
  union { unsigned int i; float f; } x; x.i = ((unsigned int)u) << 16; return x.f;
}
__device__ __forceinline__ unsigned short f2b(float f) {
  unsigned int x = __float_as_uint(f);
  return (unsigned short)((x + 0x7fffu + ((x >> 16) & 1u)) >> 16);
}

__device__ __forceinline__ void gload16(const void* g, void* l) {
  __builtin_amdgcn_global_load_lds((const __attribute__((address_space(1))) void*)g,
                                   (__attribute__((address_space(3))) void*)l,
                                   16, 0, 0);
}

// ---------------------------------------------------------------------------
// fp32 -> bf16 (elementwise, 8 elems/thread)
// ---------------------------------------------------------------------------
__global__ __launch_bounds__(256) void cvt_kernel(
    const float* __restrict__ in, unsigned short* __restrict__ out, int n) {
  int i = (blockIdx.x * 256 + threadIdx.x) * 8;
  if (i >= n) return;
  float4 v0 = *(const float4*)(in + i);
  float4 v1 = *(const float4*)(in + i + 4);
  ushort4 a, b;
  a.x = f2b(v0.x); a.y = f2b(v0.y); a.z = f2b(v0.z); a.w = f2b(v0.w);
  b.x = f2b(v1.x); b.y = f2b(v1.y); b.z = f2b(v1.z); b.w = f2b(v1.w);
  *(ushort4*)(out + i) = a;
  *(ushort4*)(out + i + 4) = b;
}

// ---------------------------------------------------------------------------
// All 5 weight transposes in one dispatch; z selects the weight.
// z=0 -> w1t, z=1 -> w2t, z=2..4 -> q/k/v into combined wqkvt [3072][1024].
// ---------------------------------------------------------------------------
__global__ __launch_bounds__(256) void transpose5_kernel(
    const float* __restrict__ w1, const float* __restrict__ w2,
    const float* __restrict__ qw, const float* __restrict__ kw,
    const float* __restrict__ vw,
    unsigned short* __restrict__ w1t, unsigned short* __restrict__ w2t,
    unsigned short* __restrict__ wqkvt) {
  __shared__ float t[32][33];
  int z = blockIdx.z;
  const float* in = (z == 0) ? w1 : (z == 1) ? w2 : (z == 2) ? qw : (z == 3) ? kw : vw;
  unsigned short* dst = (z == 0) ? w1t : (z == 1) ? w2t : wqkvt + (size_t)(z - 2) * NELEM_W;

  int tx = threadIdx.x & 31, ty = threadIdx.x >> 5;  // 32 x 8
  int r0 = blockIdx.y * 32, c0 = blockIdx.x * 32;
  #pragma unroll
  for (int i = 0; i < 32; i += 8)
    t[ty + i][tx] = in[(size_t)(r0 + ty + i) * DIMN + c0 + tx];
  __syncthreads();
  #pragma unroll
  for (int i = 0; i < 32; i += 8)
    dst[(size_t)(c0 + ty + i) * DIMN + r0 + tx] = f2b(t[tx][ty + i]);
}

// ---------------------------------------------------------------------------
// GEMM: C[M,N] = A[M,K] @ Bt[N,K]^T + bias     (plain bf16, f32 accum)
// 128x128 tile, BK=32, 256 threads (4 waves as 2x2; each wave 64x64 = 4x4
// frags of 16x16), mfma_f32_16x16x32_bf16.
// PROVEN round-1 structure: single static LDS buffer, stage -> sync ->
// ds_read+MFMA -> sync. (Round-2's runtime-indexed dbuf + prefetch
// catastrophically serialized the DMA; reverted.)
// Fragment-major LDS: each 16x32 fragment block is 1KB, lane-contiguous ->
// global_load_lds(16B) and ds_read_b128 both conflict-free by construction.
// EPI 0: relu+bf16.  EPI 1: bf16.  EPI 2: bf16, bias per 1024-col group.
// ---------------------------------------------------------------------------
template<int EPI>
__global__ __launch_bounds__(256) void gemm_kernel(
    const unsigned short* __restrict__ A, const unsigned short* __restrict__ Bt,
    const float* __restrict__ bias0, const float* __restrict__ bias1,
    const float* __restrict__ bias2,
    unsigned short* __restrict__ O, int Ndim, int Kdim) {
  __shared__ unsigned short lds[16 * 512];   // 16 KB

  const int tid  = threadIdx.x;
  const int lane = tid & 63;
  const int wave = tid >> 6;
  const int wm = wave >> 1;
  const int wn = wave & 1;
  const int frow = lane & 15;
  const int krow = lane >> 4;
  const int bm0 = blockIdx.y * 128;
  const int bn0 = blockIdx.x * 128;

  f32x4v acc[4][4] = {};

  for (int k0 = 0; k0 < Kdim; k0 += 32) {
    // stage A blocks 0..7 (rows bm0..+127), B blocks 8..15 (cols bn0..+127)
    for (int i = wave; i < 16; i += 4) {
      const unsigned short* src = (i < 8) ? A : Bt;
      int row = (i < 8) ? (bm0 + i * 16 + frow) : (bn0 + (i - 8) * 16 + frow);
      gload16(src + (size_t)row * Kdim + k0 + krow * 8, lds + i * 512);
    }
    __syncthreads();   // drains vmcnt for global_load_lds

    const short* sl = (const short*)lds;
    s16x8 a[4], b[4];
    #pragma unroll
    for (int m = 0; m < 4; ++m)
      a[m] = *(const s16x8*)(sl + (wm * 4 + m) * 512 + lane * 8);
    #pragma unroll
    for (int n = 0; n < 4; ++n)
      b[n] = *(const s16x8*)(sl + (8 + wn * 4 + n) * 512 + lane * 8);

    #pragma unroll
    for (int m = 0; m < 4; ++m)
      #pragma unroll
      for (int n = 0; n < 4; ++n)
        acc[m][n] = __builtin_amdgcn_mfma_f32_16x16x32_bf16(a[m], b[n], acc[m][n], 0, 0, 0);
    __syncthreads();
  }

  // epilogue: C row = (lane>>4)*4 + r, col = lane&15 within each 16x16 frag
  #pragma unroll
  for (int n = 0; n < 4; ++n) {
    int col = bn0 + wn * 64 + n * 16 + frow;
    float bv;
    if (EPI == 2) {
      int sel = col >> 10;
      const float* bp = (sel == 0) ? bias0 : (sel == 1) ? bias1 : bias2;
      bv = bp[col & (DIMN - 1)];
    } else {
      bv = bias0[col];
    }
    #pragma unroll
    for (int m = 0; m < 4; ++m) {
      int rbase = bm0 + wm * 64 + m * 16 + krow * 4;
      #pragma unroll
      for (int r = 0; r < 4; ++r) {
        float v = acc[m][n][r] + bv;
        if (EPI == 0) v = fmaxf(v, 0.f);
        O[(size_t)(rbase + r) * Ndim + col] = f2b(v);
      }
    }
  }
}

// ---------------------------------------------------------------------------
// Sliding-window attention on fused QKV buffer [M][3072] (q|k|v).
// One block per (b,s). q in registers; PV split 4x across waves with a
// bank-clean [wave][i][lane] partial layout.
// ---------------------------------------------------------------------------
__global__ __launch_bounds__(256) void attn_kernel(
    const unsigned short* __restrict__ qkv, float* __restrict__ out) {
  __shared__ float sc[72];
  __shared__ float wts[72];
  __shared__ float part[4][16][68];
  const float NEG_INF = -__builtin_huge_valf();
  const int ROWS = 3 * DIMN;

  int bs = blockIdx.x;
  int s = bs & (SEQ - 1);
  int tid = threadIdx.x, lane = tid & 63, wave = tid >> 6;

  // q slice (16 dims per lane) into registers, pre-scaled by 1/sqrt(1024)
  float qr[16];
  {
    const unsigned short* qp = qkv + (size_t)bs * ROWS + lane * 16;
    s16x8 q0 = *(const s16x8*)qp;
    s16x8 q1 = *(const s16x8*)(qp + 8);
    #pragma unroll
    for (int i = 0; i < 8; ++i) {
      qr[i]     = b2f((unsigned short)q0[i]) * 0.03125f;
      qr[8 + i] = b2f((unsigned short)q1[i]) * 0.03125f;
    }
  }

  const unsigned short* kbase = qkv + (size_t)(bs - s) * ROWS + DIMN;
  for (int j = wave; j < 65; j += 4) {
    int pos = s - 32 + j;
    float dot;
    if (pos >= 0 && pos < SEQ) {
      const unsigned short* kp = kbase + (size_t)pos * ROWS + lane * 16;
      s16x8 k0 = *(const s16x8*)kp;
      s16x8 k1 = *(const s16x8*)(kp + 8);
      dot = 0.f;
      #pragma unroll
      for (int i = 0; i < 8; ++i)
        dot += qr[i] * b2f((unsigned short)k0[i]) + qr[8 + i] * b2f((unsigned short)k1[i]);
      #pragma unroll
      for (int off = 32; off > 0; off >>= 1) dot += __shfl_xor(dot, off);
    } else {
      dot = NEG_INF;
    }
    if (lane == 0) sc[j] = dot;
  }
  __syncthreads();

  if (wave == 0) {
    float v0 = sc[lane];
    float v1 = (lane == 0) ? sc[64] : NEG_INF;
    float mx = fmaxf(v0, v1);
    #pragma unroll
    for (int off = 32; off > 0; off >>= 1) mx = fmaxf(mx, __shfl_xor(mx, off));
    float p0 = __expf(v0 - mx);
    float p1 = (lane == 0) ? __expf(v1 - mx) : 0.f;
    float sm = p0 + p1;
    #pragma unroll
    for (int off = 32; off > 0; off >>= 1) sm += __shfl_xor(sm, off);
    float inv = 1.f / sm;
    wts[lane] = p0 * inv;
    if (lane == 0) wts[64] = p1 * inv;
  }
  __syncthreads();

  // PV: wave w handles j = w, w+4, ...; lane covers dims lane*16..+15
  float acc[16];
  #pragma unroll
  for (int i = 0; i < 16; ++i) acc[i] = 0.f;
  const unsigned short* vbase = qkv + (size_t)(bs - s) * ROWS + 2 * DIMN;
  for (int j = wave; j < 65; j += 4) {
    int pos = s - 32 + j;
    if (pos < 0 || pos >= SEQ) continue;
    float w = wts[j];
    const unsigned short* vp = vbase + (size_t)pos * ROWS + lane * 16;
    s16x8 v0 = *(const s16x8*)vp;
    s16x8 v1 = *(const s16x8*)(vp + 8);
    #pragma unroll
    for (int i = 0; i < 8; ++i) {
      acc[i]     += w * b2f((unsigned short)v0[i]);
      acc[8 + i] += w * b2f((unsigned short)v1[i]);
    }
  }
  #pragma unroll
  for (int i = 0; i < 16; ++i) part[wave][i][lane] = acc[i];
  __syncthreads();

  // reduce 4 partials; thread handles dims d0..d0+3
  int d0 = tid * 4;
  int lsrc = d0 >> 4;
  int ibase = d0 & 15;
  float r0 = 0.f, r1 = 0.f, r2 = 0.f, r3 = 0.f;
  #pragma unroll
  for (int w = 0; w < 4; ++w) {
    r0 += part[w][ibase + 0][lsrc];
    r1 += part[w][ibase + 1][lsrc];
    r2 += part[w][ibase + 2][lsrc];
    r3 += part[w][ibase + 3][lsrc];
  }
  float4 r; r.x = r0; r.y = r1; r.z = r2; r.w = r3;
  *(float4*)(out + (size_t)bs * DIMN + d0) = r;
}

// ---------------------------------------------------------------------------
extern "C" void kernel_launch(void* const* d_in, const int* in_sizes, int n_in,
                              void* d_out, int out_size, void* d_ws, size_t ws_size,
                              hipStream_t stream) {
  const float* x  = (const float*)d_in[0];
  const float* w1 = (const float*)d_in[1];
  const float* b1 = (const float*)d_in[2];
  const float* w2 = (const float*)d_in[3];
  const float* b2 = (const float*)d_in[4];
  const float* qw = (const float*)d_in[5];
  const float* qb = (const float*)d_in[6];
  const float* kw = (const float*)d_in[7];
  const float* kb = (const float*)d_in[8];
  const float* vw = (const float*)d_in[9];
  const float* vb = (const float*)d_in[10];
  float* out = (float*)d_out;

  char* ws = (char*)d_ws;
  const size_t MB = 1024 * 1024;
  // [0:24MB) qkv (overlays x_bf [0:8) and h_bf [8:16) once they are dead)
  unsigned short* x_bf  = (unsigned short*)(ws);             // 8 MB
  unsigned short* h_bf  = (unsigned short*)(ws + 8 * MB);    // 8 MB
  unsigned short* qkv   = (unsigned short*)(ws);             // 24 MB
  unsigned short* m_bf  = (unsigned short*)(ws + 24 * MB);   // 8 MB
  unsigned short* w1t   = (unsigned short*)(ws + 32 * MB);   // 2 MB
  unsigned short* w2t   = (unsigned short*)(ws + 34 * MB);   // 2 MB
  unsigned short* wqkvt = (unsigned short*)(ws + 36 * MB);   // 6 MB

  cvt_kernel<<<NELEM_ACT / (256 * 8), 256, 0, stream>>>(x, x_bf, NELEM_ACT);
  transpose5_kernel<<<dim3(32, 32, 5), 256, 0, stream>>>(w1, w2, qw, kw, vw,
                                                         w1t, w2t, wqkvt);

  dim3 g1(DIMN / 128, MTOT / 128);     // (8, 32)
  gemm_kernel<0><<<g1, 256, 0, stream>>>(x_bf, w1t, b1, nullptr, nullptr,
                                         h_bf, DIMN, DIMN);
  gemm_kernel<1><<<g1, 256, 0, stream>>>(h_bf, w2t, b2, nullptr, nullptr,
                                         m_bf, DIMN, DIMN);
  dim3 g2(3 * DIMN / 128, MTOT / 128); // (24, 32)
  gemm_kernel<2><<<g2, 256, 0, stream>>>(m_bf, wqkvt, qb, kb, vb,
                                         qkv, 3 * DIMN, DIMN);

  attn_kernel<<<MTOT, 256, 0, stream>>>(qkv, out);
}

// Round 6
// 242.052 us; speedup vs baseline: 2.5792x; 1.1255x over previous
//
#include <hip/hip_runtime.h>
#include <cstdint>

#define DIMN 1024
#define SEQ  2048
#define BATCH 2
#define MTOT (BATCH*SEQ)      // 4096 rows
#define NELEM_ACT (MTOT*DIMN) // 4,194,304
#define NELEM_W   (DIMN*DIMN) // 1,048,576

typedef __attribute__((ext_vector_type(8))) short   s16x8;
typedef __attribute__((ext_vector_type(4))) float   f32x4v;

__device__ __forceinline__ float b2f(unsigned short u) {
  union { unsigned int i; float f; } x; x.i = ((unsigned int)u) << 16; return x.f;
}
__device__ __forceinline__ unsigned short f2b(float f) {
  unsigned int x = __float_as_uint(f);
  return (unsigned short)((x + 0x7fffu + ((x >> 16) & 1u)) >> 16);
}

__device__ __forceinline__ void gload16(const void* g, void* l) {
  __builtin_amdgcn_global_load_lds((const __attribute__((address_space(1))) void*)g,
                                   (__attribute__((address_space(3))) void*)l,
                                   16, 0, 0);
}

// ---------------------------------------------------------------------------
// fp32 -> bf16 (elementwise, 8 elems/thread)
// ---------------------------------------------------------------------------
__global__ __launch_bounds__(256) void cvt_kernel(
    const float* __restrict__ in, unsigned short* __restrict__ out, int n) {
  int i = (blockIdx.x * 256 + threadIdx.x) * 8;
  if (i >= n) return;
  float4 v0 = *(const float4*)(in + i);
  float4 v1 = *(const float4*)(in + i + 4);
  ushort4 a, b;
  a.x = f2b(v0.x); a.y = f2b(v0.y); a.z = f2b(v0.z); a.w = f2b(v0.w);
  b.x = f2b(v1.x); b.y = f2b(v1.y); b.z = f2b(v1.z); b.w = f2b(v1.w);
  *(ushort4*)(out + i) = a;
  *(ushort4*)(out + i + 4) = b;
}

// ---------------------------------------------------------------------------
// All 5 weight transposes in one dispatch; z selects the weight.
// z=0 -> w1t, z=1 -> w2t, z=2..4 -> q/k/v into combined wqkvt [3072][1024].
// ---------------------------------------------------------------------------
__global__ __launch_bounds__(256) void transpose5_kernel(
    const float* __restrict__ w1, const float* __restrict__ w2,
    const float* __restrict__ qw, const float* __restrict__ kw,
    const float* __restrict__ vw,
    unsigned short* __restrict__ w1t, unsigned short* __restrict__ w2t,
    unsigned short* __restrict__ wqkvt) {
  __shared__ float t[32][33];
  int z = blockIdx.z;
  const float* in = (z == 0) ? w1 : (z == 1) ? w2 : (z == 2) ? qw : (z == 3) ? kw : vw;
  unsigned short* dst = (z == 0) ? w1t : (z == 1) ? w2t : wqkvt + (size_t)(z - 2) * NELEM_W;

  int tx = threadIdx.x & 31, ty = threadIdx.x >> 5;  // 32 x 8
  int r0 = blockIdx.y * 32, c0 = blockIdx.x * 32;
  #pragma unroll
  for (int i = 0; i < 32; i += 8)
    t[ty + i][tx] = in[(size_t)(r0 + ty + i) * DIMN + c0 + tx];
  __syncthreads();
  #pragma unroll
  for (int i = 0; i < 32; i += 8)
    dst[(size_t)(c0 + ty + i) * DIMN + r0 + tx] = f2b(t[tx][ty + i]);
}

// ---------------------------------------------------------------------------
// GEMM: C[M,N] = A[M,K] @ Bt[N,K]^T + bias   (bf16 in, f32 accum)
// Block tile (MF*32) x (NF*32), BK=64, 256 threads = 4 waves as 2x2.
// Wave tile (MF*16)x(NF*16).  2-barrier static-buffer structure (proven).
// Fragment-major LDS (1KB 16x32 blocks): gload16 + ds_read_b128 conflict-free.
// EPI 0: relu+bf16.  EPI 1: bf16.
// EPI 2 (fused QKV, N=3072): cols 0..2047 -> qk[token][2048] (q|k);
//        cols 2048.. -> VT[d][token] transposed write, bias per group.
// ---------------------------------------------------------------------------
template<int MF, int NF, int EPI>
__global__ __launch_bounds__(256) void gemm_kernel(
    const unsigned short* __restrict__ A, const unsigned short* __restrict__ Bt,
    const float* __restrict__ bias0, const float* __restrict__ bias1,
    const float* __restrict__ bias2,
    unsigned short* __restrict__ O, unsigned short* __restrict__ O2,
    int Ndim, int Kdim) {
  constexpr int TB = (MF + NF) * 4;              // 1KB blocks per K-step
  __shared__ unsigned short lds[TB * 512];

  const int tid  = threadIdx.x;
  const int lane = tid & 63;
  const int wave = tid >> 6;
  const int wm = wave >> 1;
  const int wn = wave & 1;
  const int frow = lane & 15;
  const int krow = lane >> 4;
  const int bm0 = blockIdx.y * (MF * 32);
  const int bn0 = blockIdx.x * (NF * 32);

  f32x4v acc[MF][NF] = {};

  for (int k0 = 0; k0 < Kdim; k0 += 64) {
    #pragma unroll
    for (int t = 0; t < TB / 4; ++t) {
      int i = wave + t * 4;
      const unsigned short* src;
      if (i < MF * 4) {
        int mf = i >> 1, ds = i & 1;
        src = A + (size_t)(bm0 + mf * 16 + frow) * Kdim + k0 + ds * 32 + krow * 8;
      } else {
        int j = i - MF * 4;
        int nf = j >> 1, ds = j & 1;
        src = Bt + (size_t)(bn0 + nf * 16 + frow) * Kdim + k0 + ds * 32 + krow * 8;
      }
      gload16(src, lds + i * 512);
    }
    __syncthreads();

    const short* sl = (const short*)lds;
    #pragma unroll
    for (int ds = 0; ds < 2; ++ds) {
      s16x8 a[MF], b[NF];
      #pragma unroll
      for (int m = 0; m < MF; ++m)
        a[m] = *(const s16x8*)(sl + ((wm * MF + m) * 2 + ds) * 512 + lane * 8);
      #pragma unroll
      for (int n = 0; n < NF; ++n)
        b[n] = *(const s16x8*)(sl + (MF * 4 + (wn * NF + n) * 2 + ds) * 512 + lane * 8);
      #pragma unroll
      for (int m = 0; m < MF; ++m)
        #pragma unroll
        for (int n = 0; n < NF; ++n)
          acc[m][n] = __builtin_amdgcn_mfma_f32_16x16x32_bf16(a[m], b[n], acc[m][n], 0, 0, 0);
    }
    __syncthreads();
  }

  // epilogue: frag C row = (lane>>4)*4 + r, col = lane&15
  #pragma unroll
  for (int n = 0; n < NF; ++n) {
    int col = bn0 + wn * (NF * 16) + n * 16 + frow;
    float bv;
    if (EPI == 2) {
      int sel = col >> 10;
      const float* bp = (sel == 0) ? bias0 : (sel == 1) ? bias1 : bias2;
      bv = bp[col & (DIMN - 1)];
    } else {
      bv = bias0[col];
    }
    #pragma unroll
    for (int m = 0; m < MF; ++m) {
      int rbase = bm0 + wm * (MF * 16) + m * 16 + krow * 4;
      if (EPI == 2 && col >= 2048) {
        // transposed V write: VT[d][token], 4 consecutive tokens -> 8B store
        int d = col - 2048;
        ushort4 pk;
        pk.x = f2b(acc[m][n][0] + bv); pk.y = f2b(acc[m][n][1] + bv);
        pk.z = f2b(acc[m][n][2] + bv); pk.w = f2b(acc[m][n][3] + bv);
        *(ushort4*)(O2 + (size_t)d * MTOT + rbase) = pk;
      } else {
        #pragma unroll
        for (int r = 0; r < 4; ++r) {
          float v = acc[m][n][r] + bv;
          if (EPI == 0) v = fmaxf(v, 0.f);
          if (EPI == 2) O[(size_t)(rbase + r) * 2048 + col] = f2b(v);
          else          O[(size_t)(rbase + r) * Ndim + col] = f2b(v);
        }
      }
    }
  }
}

// ---------------------------------------------------------------------------
// MFMA sliding-window attention.  One block per 32 queries (grid 128).
// Padded key window: 96 keys [s0-32, s0+63].  4 waves: qf = w&1 (16 q rows),
// kh = w>>1 (key half for QK / d half for PV).
// S^T = K @ Q^T so softmax is lane-local per q (4-lane shfl groups) with a
// 2-half LDS combine.  P -> bf16 in padded LDS.  PV uses VT[d][token].
// ---------------------------------------------------------------------------
#define QBLK 32
#define NEGI (-1.0e30f)

__global__ __launch_bounds__(256) void attn_mfma_kernel(
    const unsigned short* __restrict__ qk,   // [MTOT][2048]  (q|k)
    const unsigned short* __restrict__ vt,   // [DIMN][MTOT]
    float* __restrict__ out) {               // [MTOT][DIMN]
  __shared__ unsigned short stage[24 * 512];   // 24 KB
  __shared__ unsigned short plds[QBLK][136];   // P bf16, padded
  __shared__ float pmax[2][QBLK];
  __shared__ float psum[2][QBLK];

  const int tid = threadIdx.x, lane = tid & 63, wave = tid >> 6;
  const int frow = lane & 15, krow = lane >> 4;
  const int tok0 = blockIdx.x * QBLK;
  const int s0 = tok0 & (SEQ - 1);
  const int bbase = tok0 - s0;
  const int qf = wave & 1;
  const int kh = wave >> 1;

  // ---------------- QK^T ----------------
  f32x4v sacc[3] = {};
  for (int d0 = 0; d0 < DIMN; d0 += 64) {
    #pragma unroll
    for (int t = 0; t < 4; ++t) {
      int i = wave + t * 4;
      const unsigned short* src;
      if (i < 4) {
        int qfs = i >> 1, ds = i & 1;
        src = qk + (size_t)(tok0 + qfs * 16 + frow) * 2048 + d0 + ds * 32 + krow * 8;
      } else {
        int j = i - 4;
        int kf = j >> 1, ds = j & 1;
        int kpos = s0 - 32 + kf * 16 + frow;
        kpos = min(max(kpos, 0), SEQ - 1);
        src = qk + (size_t)(bbase + kpos) * 2048 + 1024 + d0 + ds * 32 + krow * 8;
      }
      gload16(src, stage + i * 512);
    }
    __syncthreads();
    const short* sl = (const short*)stage;
    #pragma unroll
    for (int ds = 0; ds < 2; ++ds) {
      s16x8 bq = *(const s16x8*)(sl + (qf * 2 + ds) * 512 + lane * 8);
      #pragma unroll
      for (int f = 0; f < 3; ++f) {
        int kf = kh * 3 + f;
        s16x8 ak = *(const s16x8*)(sl + (4 + kf * 2 + ds) * 512 + lane * 8);
        sacc[f] = __builtin_amdgcn_mfma_f32_16x16x32_bf16(ak, bq, sacc[f], 0, 0, 0);
      }
    }
    __syncthreads();
  }

  // ---------------- mask + softmax ----------------
  const int qloc = qf * 16 + frow;
  const int qpos = s0 + qloc;
  float sv[3][4];
  float mx = NEGI;
  #pragma unroll
  for (int f = 0; f < 3; ++f) {
    #pragma unroll
    for (int r = 0; r < 4; ++r) {
      int kloc = (kh * 3 + f) * 16 + krow * 4 + r;
      int kpos = s0 - 32 + kloc;
      int dd = kpos - qpos;
      bool valid = (dd >= -32) && (dd <= 32) && (kpos >= 0) && (kpos < SEQ);
      float v = valid ? sacc[f][r] * 0.03125f : NEGI;
      sv[f][r] = v;
      mx = fmaxf(mx, v);
    }
  }
  mx = fmaxf(mx, __shfl_xor(mx, 16));
  mx = fmaxf(mx, __shfl_xor(mx, 32));
  if (lane < 16) pmax[kh][qf * 16 + lane] = mx;
  __syncthreads();
  float M = fmaxf(pmax[0][qloc], pmax[1][qloc]);
  float sum = 0.f;
  unsigned int pw[3][2];
  #pragma unroll
  for (int f = 0; f < 3; ++f) {
    #pragma unroll
    for (int pr = 0; pr < 2; ++pr) {
      float p0 = __expf(sv[f][2 * pr]     - M);
      float p1 = __expf(sv[f][2 * pr + 1] - M);
      sum += p0 + p1;
      pw[f][pr] = (unsigned int)f2b(p0) | ((unsigned int)f2b(p1) << 16);
    }
  }
  sum += __shfl_xor(sum, 16);
  sum += __shfl_xor(sum, 32);
  if (lane < 16) psum[kh][qf * 16 + lane] = sum;
  {
    unsigned int* pl = (unsigned int*)&plds[0][0];
    int base = qloc * 68 + (kh * 3) * 8 + krow * 2;
    #pragma unroll
    for (int f = 0; f < 3; ++f) {
      pl[base + f * 8 + 0] = pw[f][0];
      pl[base + f * 8 + 1] = pw[f][1];
    }
  }
  __syncthreads();

  // ---------------- PV ----------------
  // A-frags: P rows (this wave's qf), k = keys
  s16x8 pa[3];
  #pragma unroll
  for (int kf = 0; kf < 3; ++kf)
    pa[kf] = *(const s16x8*)((const short*)&plds[0][0] +
                             (qf * 16 + frow) * 136 + kf * 32 + krow * 8);
  float rden[4];
  #pragma unroll
  for (int r = 0; r < 4; ++r) {
    int q = qf * 16 + krow * 4 + r;
    rden[r] = 1.f / (psum[0][q] + psum[1][q]);
  }

  for (int c = 0; c < 8; ++c) {           // d-chunks of 128
    // stage VT[c*128 .. +127][t0 .. t0+95]: blocks i = kf*8 + nf
    #pragma unroll
    for (int t = 0; t < 6; ++t) {
      int i = wave + t * 4;
      int kf = i >> 3, nf = i & 7;
      int d = c * 128 + nf * 16 + frow;
      int tt = s0 - 32 + kf * 32 + krow * 8;
      tt = min(max(tt, 0), SEQ - 8);      // 8-token groups never straddle
      gload16(vt + (size_t)d * MTOT + bbase + tt, stage + i * 512);
    }
    __syncthreads();
    const short* sl = (const short*)stage;
    f32x4v oacc[4] = {};
    #pragma unroll
    for (int kf = 0; kf < 3; ++kf) {
      #pragma unroll
      for (int n = 0; n < 4; ++n) {
        int nf = kh * 4 + n;
        s16x8 bv = *(const s16x8*)(sl + (kf * 8 + nf) * 512 + lane * 8);
        oacc[n] = __builtin_amdgcn_mfma_f32_16x16x32_bf16(pa[kf], bv, oacc[n], 0, 0, 0);
      }
    }
    #pragma unroll
    for (int n = 0; n < 4; ++n) {
      int d = c * 128 + (kh * 4 + n) * 16 + frow;
      #pragma unroll
      for (int r = 0; r < 4; ++r) {
        int q = qf * 16 + krow * 4 + r;
        out[(size_t)(tok0 + q) * DIMN + d] = oacc[n][r] * rden[r];
      }
    }
    __syncthreads();
  }
}

// ---------------------------------------------------------------------------
extern "C" void kernel_launch(void* const* d_in, const int* in_sizes, int n_in,
                              void* d_out, int out_size, void* d_ws, size_t ws_size,
                              hipStream_t stream) {
  const float* x  = (const float*)d_in[0];
  const float* w1 = (const float*)d_in[1];
  const float* b1 = (const float*)d_in[2];
  const float* w2 = (const float*)d_in[3];
  const float* b2 = (const float*)d_in[4];
  const float* qw = (const float*)d_in[5];
  const float* qb = (const float*)d_in[6];
  const float* kw = (const float*)d_in[7];
  const float* kb = (const float*)d_in[8];
  const float* vw = (const float*)d_in[9];
  const float* vb = (const float*)d_in[10];
  float* out = (float*)d_out;

  char* ws = (char*)d_ws;
  const size_t MB = 1024 * 1024;
  unsigned short* x_bf  = (unsigned short*)(ws);             // 8 MB
  unsigned short* h_bf  = (unsigned short*)(ws + 8  * MB);   // 8 MB
  unsigned short* m_bf  = (unsigned short*)(ws + 16 * MB);   // 8 MB
  unsigned short* qkbuf = (unsigned short*)(ws + 24 * MB);   // 16 MB [4096][2048]
  unsigned short* vtbuf = (unsigned short*)(ws + 40 * MB);   // 8 MB  [1024][4096]
  unsigned short* w1t   = (unsigned short*)(ws + 48 * MB);   // 2 MB
  unsigned short* w2t   = (unsigned short*)(ws + 50 * MB);   // 2 MB
  unsigned short* wqkvt = (unsigned short*)(ws + 52 * MB);   // 6 MB

  cvt_kernel<<<NELEM_ACT / (256 * 8), 256, 0, stream>>>(x, x_bf, NELEM_ACT);
  transpose5_kernel<<<dim3(32, 32, 5), 256, 0, stream>>>(w1, w2, qw, kw, vw,
                                                         w1t, w2t, wqkvt);

  // MLP GEMMs: 64x128 tile -> 512 blocks (2/CU)
  dim3 g1(DIMN / 128, MTOT / 64);
  gemm_kernel<2, 4, 0><<<g1, 256, 0, stream>>>(x_bf, w1t, b1, nullptr, nullptr,
                                               h_bf, nullptr, DIMN, DIMN);
  gemm_kernel<2, 4, 1><<<g1, 256, 0, stream>>>(h_bf, w2t, b2, nullptr, nullptr,
                                               m_bf, nullptr, DIMN, DIMN);
  // fused QKV GEMM: 128x128 tile over N=3072 -> 768 blocks (3/CU)
  dim3 g2(3 * DIMN / 128, MTOT / 128);
  gemm_kernel<4, 4, 2><<<g2, 256, 0, stream>>>(m_bf, wqkvt, qb, kb, vb,
                                               qkbuf, vtbuf, 3 * DIMN, DIMN);

  attn_mfma_kernel<<<MTOT / QBLK, 256, 0, stream>>>(qkbuf, vtbuf, out);
}

// Round 7
// 234.000 us; speedup vs baseline: 2.6679x; 1.0344x over previous
//
#include <hip/hip_runtime.h>
#include <cstdint>

#define DIMN 1024
#define SEQ  2048
#define BATCH 2
#define MTOT (BATCH*SEQ)      // 4096 rows
#define NELEM_ACT (MTOT*DIMN) // 4,194,304
#define NELEM_W   (DIMN*DIMN) // 1,048,576

typedef __attribute__((ext_vector_type(8))) short   s16x8;
typedef __attribute__((ext_vector_type(4))) float   f32x4v;

__device__ __forceinline__ float b2f(unsigned short u) {
  union { unsigned int i; float f; } x; x.i = ((unsigned int)u) << 16; return x.f;
}
__device__ __forceinline__ unsigned short f2b(float f) {
  unsigned int x = __float_as_uint(f);
  return (unsigned short)((x + 0x7fffu + ((x >> 16) & 1u)) >> 16);
}

__device__ __forceinline__ void gload16(const void* g, void* l) {
  __builtin_amdgcn_global_load_lds((const __attribute__((address_space(1))) void*)g,
                                   (__attribute__((address_space(3))) void*)l,
                                   16, 0, 0);
}

// ---------------------------------------------------------------------------
// fp32 -> bf16 (elementwise, 8 elems/thread)
// ---------------------------------------------------------------------------
__global__ __launch_bounds__(256) void cvt_kernel(
    const float* __restrict__ in, unsigned short* __restrict__ out, int n) {
  int i = (blockIdx.x * 256 + threadIdx.x) * 8;
  if (i >= n) return;
  float4 v0 = *(const float4*)(in + i);
  float4 v1 = *(const float4*)(in + i + 4);
  ushort4 a, b;
  a.x = f2b(v0.x); a.y = f2b(v0.y); a.z = f2b(v0.z); a.w = f2b(v0.w);
  b.x = f2b(v1.x); b.y = f2b(v1.y); b.z = f2b(v1.z); b.w = f2b(v1.w);
  *(ushort4*)(out + i) = a;
  *(ushort4*)(out + i + 4) = b;
}

// ---------------------------------------------------------------------------
// All 5 weight transposes in one dispatch; z selects the weight.
// z=0 -> w1t, z=1 -> w2t, z=2..4 -> q/k/v into combined wqkvt [3072][1024].
// ---------------------------------------------------------------------------
__global__ __launch_bounds__(256) void transpose5_kernel(
    const float* __restrict__ w1, const float* __restrict__ w2,
    const float* __restrict__ qw, const float* __restrict__ kw,
    const float* __restrict__ vw,
    unsigned short* __restrict__ w1t, unsigned short* __restrict__ w2t,
    unsigned short* __restrict__ wqkvt) {
  __shared__ float t[32][33];
  int z = blockIdx.z;
  const float* in = (z == 0) ? w1 : (z == 1) ? w2 : (z == 2) ? qw : (z == 3) ? kw : vw;
  unsigned short* dst = (z == 0) ? w1t : (z == 1) ? w2t : wqkvt + (size_t)(z - 2) * NELEM_W;

  int tx = threadIdx.x & 31, ty = threadIdx.x >> 5;  // 32 x 8
  int r0 = blockIdx.y * 32, c0 = blockIdx.x * 32;
  #pragma unroll
  for (int i = 0; i < 32; i += 8)
    t[ty + i][tx] = in[(size_t)(r0 + ty + i) * DIMN + c0 + tx];
  __syncthreads();
  #pragma unroll
  for (int i = 0; i < 32; i += 8)
    dst[(size_t)(c0 + ty + i) * DIMN + r0 + tx] = f2b(t[tx][ty + i]);
}

// ---------------------------------------------------------------------------
// GEMM: C[M,N] = A[M,K] @ Bt[N,K]^T + bias   (bf16 in, f32 accum)
// Block tile (MF*32) x (NF*32), BK=64, 256 threads = 4 waves as 2x2.
// 2-PHASE STATIC DOUBLE-BUFFER (T3 minimum recipe, m230/m228d-proven):
//   K-loop unrolled x2 with COMPILE-TIME buffer pointers (lds / lds+TB*512);
//   per step: sync(cur ready) -> issue stage(next) -> compute(cur).
//   One barrier per K-step; staging latency hides under MFMA of cur.
//   (Round-2's runtime-indexed buffer flip serialized the DMA - rule #20.)
// Fragment-major LDS (1KB 16x32 blocks): gload16 + ds_read_b128 conflict-free.
// EPI 0: relu+bf16.  EPI 1: bf16.
// EPI 2 (fused QKV, N=3072): cols 0..2047 -> qk[token][2048] (q|k);
//        cols 2048.. -> VT[d][token] transposed write, bias per group.
// Requires Kdim % 128 == 0 (even number of BK=64 steps).
// ---------------------------------------------------------------------------
template<int MF, int NF, int EPI>
__global__ __launch_bounds__(256) void gemm_kernel(
    const unsigned short* __restrict__ A, const unsigned short* __restrict__ Bt,
    const float* __restrict__ bias0, const float* __restrict__ bias1,
    const float* __restrict__ bias2,
    unsigned short* __restrict__ O, unsigned short* __restrict__ O2,
    int Ndim, int Kdim) {
  constexpr int TB = (MF + NF) * 4;              // 1KB blocks per buffer
  __shared__ unsigned short lds[2 * TB * 512];

  const int tid  = threadIdx.x;
  const int lane = tid & 63;
  const int wave = tid >> 6;
  const int wm = wave >> 1;
  const int wn = wave & 1;
  const int frow = lane & 15;
  const int krow = lane >> 4;
  const int bm0 = blockIdx.y * (MF * 32);
  const int bn0 = blockIdx.x * (NF * 32);

  f32x4v acc[MF][NF] = {};

  auto stage = [&](unsigned short* dst, int k0) {
    #pragma unroll
    for (int t = 0; t < TB / 4; ++t) {
      int i = wave + t * 4;
      const unsigned short* src;
      if (i < MF * 4) {
        int mf = i >> 1, ds = i & 1;
        src = A + (size_t)(bm0 + mf * 16 + frow) * Kdim + k0 + ds * 32 + krow * 8;
      } else {
        int j = i - MF * 4;
        int nf = j >> 1, ds = j & 1;
        src = Bt + (size_t)(bn0 + nf * 16 + frow) * Kdim + k0 + ds * 32 + krow * 8;
      }
      gload16(src, dst + i * 512);
    }
  };

  auto compute = [&](const unsigned short* buf) {
    const short* sl = (const short*)buf;
    #pragma unroll
    for (int ds = 0; ds < 2; ++ds) {
      s16x8 a[MF], b[NF];
      #pragma unroll
      for (int m = 0; m < MF; ++m)
        a[m] = *(const s16x8*)(sl + ((wm * MF + m) * 2 + ds) * 512 + lane * 8);
      #pragma unroll
      for (int n = 0; n < NF; ++n)
        b[n] = *(const s16x8*)(sl + (MF * 4 + (wn * NF + n) * 2 + ds) * 512 + lane * 8);
      #pragma unroll
      for (int m = 0; m < MF; ++m)
        #pragma unroll
        for (int n = 0; n < NF; ++n)
          acc[m][n] = __builtin_amdgcn_mfma_f32_16x16x32_bf16(a[m], b[n], acc[m][n], 0, 0, 0);
    }
  };

  const int nt = Kdim >> 6;        // BK=64 steps; nt even (Kdim=1024 -> 16)
  stage(lds, 0);
  for (int t = 0; t < nt; t += 2) {
    __syncthreads();                              // buf0(t) staged (vmcnt drained)
    if (t + 1 < nt) stage(lds + TB * 512, (t + 1) << 6);
    compute(lds);
    __syncthreads();                              // buf1(t+1) staged; buf0 free
    if (t + 2 < nt) stage(lds, (t + 2) << 6);
    compute(lds + TB * 512);
  }

  // epilogue: frag C row = (lane>>4)*4 + r, col = lane&15
  #pragma unroll
  for (int n = 0; n < NF; ++n) {
    int col = bn0 + wn * (NF * 16) + n * 16 + frow;
    float bv;
    if (EPI == 2) {
      int sel = col >> 10;
      const float* bp = (sel == 0) ? bias0 : (sel == 1) ? bias1 : bias2;
      bv = bp[col & (DIMN - 1)];
    } else {
      bv = bias0[col];
    }
    #pragma unroll
    for (int m = 0; m < MF; ++m) {
      int rbase = bm0 + wm * (MF * 16) + m * 16 + krow * 4;
      if (EPI == 2 && col >= 2048) {
        // transposed V write: VT[d][token], 4 consecutive tokens -> 8B store
        int d = col - 2048;
        ushort4 pk;
        pk.x = f2b(acc[m][n][0] + bv); pk.y = f2b(acc[m][n][1] + bv);
        pk.z = f2b(acc[m][n][2] + bv); pk.w = f2b(acc[m][n][3] + bv);
        *(ushort4*)(O2 + (size_t)d * MTOT + rbase) = pk;
      } else {
        #pragma unroll
        for (int r = 0; r < 4; ++r) {
          float v = acc[m][n][r] + bv;
          if (EPI == 0) v = fmaxf(v, 0.f);
          if (EPI == 2) O[(size_t)(rbase + r) * 2048 + col] = f2b(v);
          else          O[(size_t)(rbase + r) * Ndim + col] = f2b(v);
        }
      }
    }
  }
}

// ---------------------------------------------------------------------------
// MFMA sliding-window attention.  One block per 32 queries (grid 128).
// Padded key window: 96 keys [s0-32, s0+63].  4 waves: qf = w&1 (16 q rows),
// kh = w>>1 (key half for QK / d half for PV).
// S^T = K @ Q^T so softmax is lane-local per q (4-lane shfl groups) with a
// 2-half LDS combine.  P -> bf16 in padded LDS.  PV uses VT[d][token].
// ---------------------------------------------------------------------------
#define QBLK 32
#define NEGI (-1.0e30f)

__global__ __launch_bounds__(256) void attn_mfma_kernel(
    const unsigned short* __restrict__ qk,   // [MTOT][2048]  (q|k)
    const unsigned short* __restrict__ vt,   // [DIMN][MTOT]
    float* __restrict__ out) {               // [MTOT][DIMN]
  __shared__ unsigned short stage[24 * 512];   // 24 KB
  __shared__ unsigned short plds[QBLK][136];   // P bf16, padded
  __shared__ float pmax[2][QBLK];
  __shared__ float psum[2][QBLK];

  const int tid = threadIdx.x, lane = tid & 63, wave = tid >> 6;
  const int frow = lane & 15, krow = lane >> 4;
  const int tok0 = blockIdx.x * QBLK;
  const int s0 = tok0 & (SEQ - 1);
  const int bbase = tok0 - s0;
  const int qf = wave & 1;
  const int kh = wave >> 1;

  // ---------------- QK^T ----------------
  f32x4v sacc[3] = {};
  for (int d0 = 0; d0 < DIMN; d0 += 64) {
    #pragma unroll
    for (int t = 0; t < 4; ++t) {
      int i = wave + t * 4;
      const unsigned short* src;
      if (i < 4) {
        int qfs = i >> 1, ds = i & 1;
        src = qk + (size_t)(tok0 + qfs * 16 + frow) * 2048 + d0 + ds * 32 + krow * 8;
      } else {
        int j = i - 4;
        int kf = j >> 1, ds = j & 1;
        int kpos = s0 - 32 + kf * 16 + frow;
        kpos = min(max(kpos, 0), SEQ - 1);
        src = qk + (size_t)(bbase + kpos) * 2048 + 1024 + d0 + ds * 32 + krow * 8;
      }
      gload16(src, stage + i * 512);
    }
    __syncthreads();
    const short* sl = (const short*)stage;
    #pragma unroll
    for (int ds = 0; ds < 2; ++ds) {
      s16x8 bq = *(const s16x8*)(sl + (qf * 2 + ds) * 512 + lane * 8);
      #pragma unroll
      for (int f = 0; f < 3; ++f) {
        int kf = kh * 3 + f;
        s16x8 ak = *(const s16x8*)(sl + (4 + kf * 2 + ds) * 512 + lane * 8);
        sacc[f] = __builtin_amdgcn_mfma_f32_16x16x32_bf16(ak, bq, sacc[f], 0, 0, 0);
      }
    }
    __syncthreads();
  }

  // ---------------- mask + softmax ----------------
  const int qloc = qf * 16 + frow;
  const int qpos = s0 + qloc;
  float sv[3][4];
  float mx = NEGI;
  #pragma unroll
  for (int f = 0; f < 3; ++f) {
    #pragma unroll
    for (int r = 0; r < 4; ++r) {
      int kloc = (kh * 3 + f) * 16 + krow * 4 + r;
      int kpos = s0 - 32 + kloc;
      int dd = kpos - qpos;
      bool valid = (dd >= -32) && (dd <= 32) && (kpos >= 0) && (kpos < SEQ);
      float v = valid ? sacc[f][r] * 0.03125f : NEGI;
      sv[f][r] = v;
      mx = fmaxf(mx, v);
    }
  }
  mx = fmaxf(mx, __shfl_xor(mx, 16));
  mx = fmaxf(mx, __shfl_xor(mx, 32));
  if (lane < 16) pmax[kh][qf * 16 + lane] = mx;
  __syncthreads();
  float M = fmaxf(pmax[0][qloc], pmax[1][qloc]);
  float sum = 0.f;
  unsigned int pw[3][2];
  #pragma unroll
  for (int f = 0; f < 3; ++f) {
    #pragma unroll
    for (int pr = 0; pr < 2; ++pr) {
      float p0 = __expf(sv[f][2 * pr]     - M);
      float p1 = __expf(sv[f][2 * pr + 1] - M);
      sum += p0 + p1;
      pw[f][pr] = (unsigned int)f2b(p0) | ((unsigned int)f2b(p1) << 16);
    }
  }
  sum += __shfl_xor(sum, 16);
  sum += __shfl_xor(sum, 32);
  if (lane < 16) psum[kh][qf * 16 + lane] = sum;
  {
    unsigned int* pl = (unsigned int*)&plds[0][0];
    int base = qloc * 68 + (kh * 3) * 8 + krow * 2;
    #pragma unroll
    for (int f = 0; f < 3; ++f) {
      pl[base + f * 8 + 0] = pw[f][0];
      pl[base + f * 8 + 1] = pw[f][1];
    }
  }
  __syncthreads();

  // ---------------- PV ----------------
  // A-frags: P rows (this wave's qf), k = keys
  s16x8 pa[3];
  #pragma unroll
  for (int kf = 0; kf < 3; ++kf)
    pa[kf] = *(const s16x8*)((const short*)&plds[0][0] +
                             (qf * 16 + frow) * 136 + kf * 32 + krow * 8);
  float rden[4];
  #pragma unroll
  for (int r = 0; r < 4; ++r) {
    int q = qf * 16 + krow * 4 + r;
    rden[r] = 1.f / (psum[0][q] + psum[1][q]);
  }

  for (int c = 0; c < 8; ++c) {           // d-chunks of 128
    // stage VT[c*128 .. +127][t0 .. t0+95]: blocks i = kf*8 + nf
    #pragma unroll
    for (int t = 0; t < 6; ++t) {
      int i = wave + t * 4;
      int kf = i >> 3, nf = i & 7;
      int d = c * 128 + nf * 16 + frow;
      int tt = s0 - 32 + kf * 32 + krow * 8;
      tt = min(max(tt, 0), SEQ - 8);      // 8-token groups never straddle
      gload16(vt + (size_t)d * MTOT + bbase + tt, stage + i * 512);
    }
    __syncthreads();
    const short* sl = (const short*)stage;
    f32x4v oacc[4] = {};
    #pragma unroll
    for (int kf = 0; kf < 3; ++kf) {
      #pragma unroll
      for (int n = 0; n < 4; ++n) {
        int nf = kh * 4 + n;
        s16x8 bv = *(const s16x8*)(sl + (kf * 8 + nf) * 512 + lane * 8);
        oacc[n] = __builtin_amdgcn_mfma_f32_16x16x32_bf16(pa[kf], bv, oacc[n], 0, 0, 0);
      }
    }
    #pragma unroll
    for (int n = 0; n < 4; ++n) {
      int d = c * 128 + (kh * 4 + n) * 16 + frow;
      #pragma unroll
      for (int r = 0; r < 4; ++r) {
        int q = qf * 16 + krow * 4 + r;
        out[(size_t)(tok0 + q) * DIMN + d] = oacc[n][r] * rden[r];
      }
    }
    __syncthreads();
  }
}

// ---------------------------------------------------------------------------
extern "C" void kernel_launch(void* const* d_in, const int* in_sizes, int n_in,
                              void* d_out, int out_size, void* d_ws, size_t ws_size,
                              hipStream_t stream) {
  const float* x  = (const float*)d_in[0];
  const float* w1 = (const float*)d_in[1];
  const float* b1 = (const float*)d_in[2];
  const float* w2 = (const float*)d_in[3];
  const float* b2 = (const float*)d_in[4];
  const float* qw = (const float*)d_in[5];
  const float* qb = (const float*)d_in[6];
  const float* kw = (const float*)d_in[7];
  const float* kb = (const float*)d_in[8];
  const float* vw = (const float*)d_in[9];
  const float* vb = (const float*)d_in[10];
  float* out = (float*)d_out;

  char* ws = (char*)d_ws;
  const size_t MB = 1024 * 1024;
  unsigned short* x_bf  = (unsigned short*)(ws);             // 8 MB
  unsigned short* h_bf  = (unsigned short*)(ws + 8  * MB);   // 8 MB
  unsigned short* m_bf  = (unsigned short*)(ws + 16 * MB);   // 8 MB
  unsigned short* qkbuf = (unsigned short*)(ws + 24 * MB);   // 16 MB [4096][2048]
  unsigned short* vtbuf = (unsigned short*)(ws + 40 * MB);   // 8 MB  [1024][4096]
  unsigned short* w1t   = (unsigned short*)(ws + 48 * MB);   // 2 MB
  unsigned short* w2t   = (unsigned short*)(ws + 50 * MB);   // 2 MB
  unsigned short* wqkvt = (unsigned short*)(ws + 52 * MB);   // 6 MB

  cvt_kernel<<<NELEM_ACT / (256 * 8), 256, 0, stream>>>(x, x_bf, NELEM_ACT);
  transpose5_kernel<<<dim3(32, 32, 5), 256, 0, stream>>>(w1, w2, qw, kw, vw,
                                                         w1t, w2t, wqkvt);

  // MLP GEMMs: 64x128 tile -> 512 blocks (2/CU), LDS 2x24KB
  dim3 g1(DIMN / 128, MTOT / 64);
  gemm_kernel<2, 4, 0><<<g1, 256, 0, stream>>>(x_bf, w1t, b1, nullptr, nullptr,
                                               h_bf, nullptr, DIMN, DIMN);
  gemm_kernel<2, 4, 1><<<g1, 256, 0, stream>>>(h_bf, w2t, b2, nullptr, nullptr,
                                               m_bf, nullptr, DIMN, DIMN);
  // fused QKV GEMM: 128x128 tile over N=3072 -> 768 blocks, LDS 2x32KB
  dim3 g2(3 * DIMN / 128, MTOT / 128);
  gemm_kernel<4, 4, 2><<<g2, 256, 0, stream>>>(m_bf, wqkvt, qb, kb, vb,
                                               qkbuf, vtbuf, 3 * DIMN, DIMN);

  attn_mfma_kernel<<<MTOT / QBLK, 256, 0, stream>>>(qkbuf, vtbuf, out);
}

// Round 8
// 229.147 us; speedup vs baseline: 2.7244x; 1.0212x over previous
//
#include <hip/hip_runtime.h>
#include <cstdint>

#define DIMN 1024
#define SEQ  2048
#define BATCH 2
#define MTOT (BATCH*SEQ)      // 4096 rows
#define NELEM_ACT (MTOT*DIMN) // 4,194,304
#define NELEM_W   (DIMN*DIMN) // 1,048,576

typedef __attribute__((ext_vector_type(8))) short   s16x8;
typedef __attribute__((ext_vector_type(4))) float   f32x4v;

__device__ __forceinline__ float b2f(unsigned short u) {
  union { unsigned int i; float f; } x; x.i = ((unsigned int)u) << 16; return x.f;
}
__device__ __forceinline__ unsigned short f2b(float f) {
  unsigned int x = __float_as_uint(f);
  return (unsigned short)((x + 0x7fffu + ((x >> 16) & 1u)) >> 16);
}

__device__ __forceinline__ void gload16(const void* g, void* l) {
  __builtin_amdgcn_global_load_lds((const __attribute__((address_space(1))) void*)g,
                                   (__attribute__((address_space(3))) void*)l,
                                   16, 0, 0);
}

// counted vmcnt wait with literal immediates (T4)
template<int N> __device__ __forceinline__ void waitvm() {
  static_assert(N == 0 || N == 6 || N == 8, "add a case");
  if constexpr (N == 0) asm volatile("s_waitcnt vmcnt(0)" ::: "memory");
  else if constexpr (N == 6) asm volatile("s_waitcnt vmcnt(6)" ::: "memory");
  else if constexpr (N == 8) asm volatile("s_waitcnt vmcnt(8)" ::: "memory");
}

// ---------------------------------------------------------------------------
// fp32 -> bf16 (elementwise, 8 elems/thread)
// ---------------------------------------------------------------------------
__global__ __launch_bounds__(256) void cvt_kernel(
    const float* __restrict__ in, unsigned short* __restrict__ out, int n) {
  int i = (blockIdx.x * 256 + threadIdx.x) * 8;
  if (i >= n) return;
  float4 v0 = *(const float4*)(in + i);
  float4 v1 = *(const float4*)(in + i + 4);
  ushort4 a, b;
  a.x = f2b(v0.x); a.y = f2b(v0.y); a.z = f2b(v0.z); a.w = f2b(v0.w);
  b.x = f2b(v1.x); b.y = f2b(v1.y); b.z = f2b(v1.z); b.w = f2b(v1.w);
  *(ushort4*)(out + i) = a;
  *(ushort4*)(out + i + 4) = b;
}

// ---------------------------------------------------------------------------
// All 5 weight transposes in one dispatch; z selects the weight.
// ---------------------------------------------------------------------------
__global__ __launch_bounds__(256) void transpose5_kernel(
    const float* __restrict__ w1, const float* __restrict__ w2,
    const float* __restrict__ qw, const float* __restrict__ kw,
    const float* __restrict__ vw,
    unsigned short* __restrict__ w1t, unsigned short* __restrict__ w2t,
    unsigned short* __restrict__ wqkvt) {
  __shared__ float t[32][33];
  int z = blockIdx.z;
  const float* in = (z == 0) ? w1 : (z == 1) ? w2 : (z == 2) ? qw : (z == 3) ? kw : vw;
  unsigned short* dst = (z == 0) ? w1t : (z == 1) ? w2t : wqkvt + (size_t)(z - 2) * NELEM_W;

  int tx = threadIdx.x & 31, ty = threadIdx.x >> 5;  // 32 x 8
  int r0 = blockIdx.y * 32, c0 = blockIdx.x * 32;
  #pragma unroll
  for (int i = 0; i < 32; i += 8)
    t[ty + i][tx] = in[(size_t)(r0 + ty + i) * DIMN + c0 + tx];
  __syncthreads();
  #pragma unroll
  for (int i = 0; i < 32; i += 8)
    dst[(size_t)(c0 + ty + i) * DIMN + r0 + tx] = f2b(t[tx][ty + i]);
}

// ---------------------------------------------------------------------------
// GEMM: C[M,N] = A[M,K] @ Bt[N,K]^T + bias   (bf16 in, f32 accum)
// Block tile (MF*32) x (NF*32), BK=64, 256 threads = 4 waves as 2x2.
// T4 COUNTED-VMCNT DOUBLE BUFFER (m218-proven lever):
//   raw s_barrier (no implicit vmcnt drain) + s_waitcnt vmcnt(NL) so the
//   next tile's NL loads stay in flight across the barrier; per phase:
//   waitvm<NL> -> barrier -> compute(cur) -> barrier -> stage(cur, t+2).
//   Tail phases use vmcnt(0).  sched_barrier(0) after wait-barrier (rule 18).
// T1 bijective XCD swizzle (nwg%8==0): each XCD gets a contiguous tile
//   chunk sharing A-panels -> L2 locality.
// Fragment-major LDS (1KB 16x32 blocks): gload16 + ds_read_b128 conflict-free.
// EPI 0: relu+bf16.  EPI 1: bf16.
// EPI 2 (fused QKV, N=3072): cols 0..2047 -> qk[token][2048] (q|k);
//        cols 2048.. -> VT[d][token] transposed write, bias per group.
// ---------------------------------------------------------------------------
template<int MF, int NF, int EPI>
__global__ __launch_bounds__(256) void gemm_kernel(
    const unsigned short* __restrict__ A, const unsigned short* __restrict__ Bt,
    const float* __restrict__ bias0, const float* __restrict__ bias1,
    const float* __restrict__ bias2,
    unsigned short* __restrict__ O, unsigned short* __restrict__ O2,
    int Ndim, int Kdim) {
  constexpr int TB = (MF + NF) * 4;              // 1KB blocks per buffer
  constexpr int NL = TB / 4;                     // per-thread loads per stage
  __shared__ unsigned short lds[2 * TB * 512];

  const int tid  = threadIdx.x;
  const int lane = tid & 63;
  const int wave = tid >> 6;
  const int wm = wave >> 1;
  const int wn = wave & 1;
  const int frow = lane & 15;
  const int krow = lane >> 4;

  // T1: bijective XCD swizzle (nwg multiple of 8)
  const int nwg = gridDim.x * gridDim.y;
  const int orig = blockIdx.y * gridDim.x + blockIdx.x;
  const int tile = (orig & 7) * (nwg >> 3) + (orig >> 3);
  const int bx = tile % gridDim.x;
  const int by = tile / gridDim.x;
  const int bm0 = by * (MF * 32);
  const int bn0 = bx * (NF * 32);

  f32x4v acc[MF][NF] = {};

  auto stage = [&](unsigned short* dst, int k0) {
    #pragma unroll
    for (int t = 0; t < NL; ++t) {
      int i = wave + t * 4;
      const unsigned short* src;
      if (i < MF * 4) {
        int mf = i >> 1, ds = i & 1;
        src = A + (size_t)(bm0 + mf * 16 + frow) * Kdim + k0 + ds * 32 + krow * 8;
      } else {
        int j = i - MF * 4;
        int nf = j >> 1, ds = j & 1;
        src = Bt + (size_t)(bn0 + nf * 16 + frow) * Kdim + k0 + ds * 32 + krow * 8;
      }
      gload16(src, dst + i * 512);
    }
  };

  auto compute = [&](const unsigned short* buf) {
    const short* sl = (const short*)buf;
    #pragma unroll
    for (int ds = 0; ds < 2; ++ds) {
      s16x8 a[MF], b[NF];
      #pragma unroll
      for (int m = 0; m < MF; ++m)
        a[m] = *(const s16x8*)(sl + ((wm * MF + m) * 2 + ds) * 512 + lane * 8);
      #pragma unroll
      for (int n = 0; n < NF; ++n)
        b[n] = *(const s16x8*)(sl + (MF * 4 + (wn * NF + n) * 2 + ds) * 512 + lane * 8);
      #pragma unroll
      for (int m = 0; m < MF; ++m)
        #pragma unroll
        for (int n = 0; n < NF; ++n)
          acc[m][n] = __builtin_amdgcn_mfma_f32_16x16x32_bf16(a[m], b[n], acc[m][n], 0, 0, 0);
    }
  };

  unsigned short* lds0 = lds;
  unsigned short* lds1 = lds + TB * 512;
  const int nt = Kdim >> 6;        // BK=64 steps; nt even (Kdim=1024 -> 16)

  stage(lds0, 0);
  stage(lds1, 64);
  for (int t = 0; t < nt; t += 2) {
    // --- phase A: buf0 = K-step t ---
    bool pfA = (t + 2 < nt);       // uniform
    if (pfA) waitvm<NL>(); else waitvm<0>();
    __builtin_amdgcn_s_barrier();
    __builtin_amdgcn_sched_barrier(0);
    compute(lds0);
    __builtin_amdgcn_s_barrier();  // all waves done reading buf0
    if (pfA) stage(lds0, (t + 2) << 6);
    // --- phase B: buf1 = K-step t+1 ---
    bool pfB = (t + 3 < nt);
    if (pfA) { if (pfB) waitvm<NL>(); else waitvm<0>(); } else waitvm<0>();
    __builtin_amdgcn_s_barrier();
    __builtin_amdgcn_sched_barrier(0);
    compute(lds1);
    __builtin_amdgcn_s_barrier();
    if (pfB) stage(lds1, (t + 3) << 6);
  }

  // epilogue: frag C row = (lane>>4)*4 + r, col = lane&15
  #pragma unroll
  for (int n = 0; n < NF; ++n) {
    int col = bn0 + wn * (NF * 16) + n * 16 + frow;
    float bv;
    if (EPI == 2) {
      int sel = col >> 10;
      const float* bp = (sel == 0) ? bias0 : (sel == 1) ? bias1 : bias2;
      bv = bp[col & (DIMN - 1)];
    } else {
      bv = bias0[col];
    }
    #pragma unroll
    for (int m = 0; m < MF; ++m) {
      int rbase = bm0 + wm * (MF * 16) + m * 16 + krow * 4;
      if (EPI == 2 && col >= 2048) {
        // transposed V write: VT[d][token], 4 consecutive tokens -> 8B store
        int d = col - 2048;
        ushort4 pk;
        pk.x = f2b(acc[m][n][0] + bv); pk.y = f2b(acc[m][n][1] + bv);
        pk.z = f2b(acc[m][n][2] + bv); pk.w = f2b(acc[m][n][3] + bv);
        *(ushort4*)(O2 + (size_t)d * MTOT + rbase) = pk;
      } else {
        #pragma unroll
        for (int r = 0; r < 4; ++r) {
          float v = acc[m][n][r] + bv;
          if (EPI == 0) v = fmaxf(v, 0.f);
          if (EPI == 2) O[(size_t)(rbase + r) * 2048 + col] = f2b(v);
          else          O[(size_t)(rbase + r) * Ndim + col] = f2b(v);
        }
      }
    }
  }
}

// ---------------------------------------------------------------------------
// MFMA sliding-window attention.  One block per 32 queries (grid 128).
// Padded key window: 96 keys [s0-32, s0+63].  4 waves: qf = w&1 (16 q rows),
// kh = w>>1 (key half for QK / d half for PV).
// S^T = K @ Q^T so softmax is lane-local per q (4-lane shfl groups) with a
// 2-half LDS combine.  P -> bf16 in padded LDS.  PV uses VT[d][token].
// (unchanged this round for attribution; counted-vmcnt port is next)
// ---------------------------------------------------------------------------
#define QBLK 32
#define NEGI (-1.0e30f)

__global__ __launch_bounds__(256) void attn_mfma_kernel(
    const unsigned short* __restrict__ qk,   // [MTOT][2048]  (q|k)
    const unsigned short* __restrict__ vt,   // [DIMN][MTOT]
    float* __restrict__ out) {               // [MTOT][DIMN]
  __shared__ unsigned short stage[24 * 512];   // 24 KB
  __shared__ unsigned short plds[QBLK][136];   // P bf16, padded
  __shared__ float pmax[2][QBLK];
  __shared__ float psum[2][QBLK];

  const int tid = threadIdx.x, lane = tid & 63, wave = tid >> 6;
  const int frow = lane & 15, krow = lane >> 4;
  const int tok0 = blockIdx.x * QBLK;
  const int s0 = tok0 & (SEQ - 1);
  const int bbase = tok0 - s0;
  const int qf = wave & 1;
  const int kh = wave >> 1;

  // ---------------- QK^T ----------------
  f32x4v sacc[3] = {};
  for (int d0 = 0; d0 < DIMN; d0 += 64) {
    #pragma unroll
    for (int t = 0; t < 4; ++t) {
      int i = wave + t * 4;
      const unsigned short* src;
      if (i < 4) {
        int qfs = i >> 1, ds = i & 1;
        src = qk + (size_t)(tok0 + qfs * 16 + frow) * 2048 + d0 + ds * 32 + krow * 8;
      } else {
        int j = i - 4;
        int kf = j >> 1, ds = j & 1;
        int kpos = s0 - 32 + kf * 16 + frow;
        kpos = min(max(kpos, 0), SEQ - 1);
        src = qk + (size_t)(bbase + kpos) * 2048 + 1024 + d0 + ds * 32 + krow * 8;
      }
      gload16(src, stage + i * 512);
    }
    __syncthreads();
    const short* sl = (const short*)stage;
    #pragma unroll
    for (int ds = 0; ds < 2; ++ds) {
      s16x8 bq = *(const s16x8*)(sl + (qf * 2 + ds) * 512 + lane * 8);
      #pragma unroll
      for (int f = 0; f < 3; ++f) {
        int kf = kh * 3 + f;
        s16x8 ak = *(const s16x8*)(sl + (4 + kf * 2 + ds) * 512 + lane * 8);
        sacc[f] = __builtin_amdgcn_mfma_f32_16x16x32_bf16(ak, bq, sacc[f], 0, 0, 0);
      }
    }
    __syncthreads();
  }

  // ---------------- mask + softmax ----------------
  const int qloc = qf * 16 + frow;
  const int qpos = s0 + qloc;
  float sv[3][4];
  float mx = NEGI;
  #pragma unroll
  for (int f = 0; f < 3; ++f) {
    #pragma unroll
    for (int r = 0; r < 4; ++r) {
      int kloc = (kh * 3 + f) * 16 + krow * 4 + r;
      int kpos = s0 - 32 + kloc;
      int dd = kpos - qpos;
      bool valid = (dd >= -32) && (dd <= 32) && (kpos >= 0) && (kpos < SEQ);
      float v = valid ? sacc[f][r] * 0.03125f : NEGI;
      sv[f][r] = v;
      mx = fmaxf(mx, v);
    }
  }
  mx = fmaxf(mx, __shfl_xor(mx, 16));
  mx = fmaxf(mx, __shfl_xor(mx, 32));
  if (lane < 16) pmax[kh][qf * 16 + lane] = mx;
  __syncthreads();
  float M = fmaxf(pmax[0][qloc], pmax[1][qloc]);
  float sum = 0.f;
  unsigned int pw[3][2];
  #pragma unroll
  for (int f = 0; f < 3; ++f) {
    #pragma unroll
    for (int pr = 0; pr < 2; ++pr) {
      float p0 = __expf(sv[f][2 * pr]     - M);
      float p1 = __expf(sv[f][2 * pr + 1] - M);
      sum += p0 + p1;
      pw[f][pr] = (unsigned int)f2b(p0) | ((unsigned int)f2b(p1) << 16);
    }
  }
  sum += __shfl_xor(sum, 16);
  sum += __shfl_xor(sum, 32);
  if (lane < 16) psum[kh][qf * 16 + lane] = sum;
  {
    unsigned int* pl = (unsigned int*)&plds[0][0];
    int base = qloc * 68 + (kh * 3) * 8 + krow * 2;
    #pragma unroll
    for (int f = 0; f < 3; ++f) {
      pl[base + f * 8 + 0] = pw[f][0];
      pl[base + f * 8 + 1] = pw[f][1];
    }
  }
  __syncthreads();

  // ---------------- PV ----------------
  s16x8 pa[3];
  #pragma unroll
  for (int kf = 0; kf < 3; ++kf)
    pa[kf] = *(const s16x8*)((const short*)&plds[0][0] +
                             (qf * 16 + frow) * 136 + kf * 32 + krow * 8);
  float rden[4];
  #pragma unroll
  for (int r = 0; r < 4; ++r) {
    int q = qf * 16 + krow * 4 + r;
    rden[r] = 1.f / (psum[0][q] + psum[1][q]);
  }

  for (int c = 0; c < 8; ++c) {           // d-chunks of 128
    #pragma unroll
    for (int t = 0; t < 6; ++t) {
      int i = wave + t * 4;
      int kf = i >> 3, nf = i & 7;
      int d = c * 128 + nf * 16 + frow;
      int tt = s0 - 32 + kf * 32 + krow * 8;
      tt = min(max(tt, 0), SEQ - 8);      // 8-token groups never straddle
      gload16(vt + (size_t)d * MTOT + bbase + tt, stage + i * 512);
    }
    __syncthreads();
    const short* sl = (const short*)stage;
    f32x4v oacc[4] = {};
    #pragma unroll
    for (int kf = 0; kf < 3; ++kf) {
      #pragma unroll
      for (int n = 0; n < 4; ++n) {
        int nf = kh * 4 + n;
        s16x8 bv = *(const s16x8*)(sl + (kf * 8 + nf) * 512 + lane * 8);
        oacc[n] = __builtin_amdgcn_mfma_f32_16x16x32_bf16(pa[kf], bv, oacc[n], 0, 0, 0);
      }
    }
    #pragma unroll
    for (int n = 0; n < 4; ++n) {
      int d = c * 128 + (kh * 4 + n) * 16 + frow;
      #pragma unroll
      for (int r = 0; r < 4; ++r) {
        int q = qf * 16 + krow * 4 + r;
        out[(size_t)(tok0 + q) * DIMN + d] = oacc[n][r] * rden[r];
      }
    }
    __syncthreads();
  }
}

// ---------------------------------------------------------------------------
extern "C" void kernel_launch(void* const* d_in, const int* in_sizes, int n_in,
                              void* d_out, int out_size, void* d_ws, size_t ws_size,
                              hipStream_t stream) {
  const float* x  = (const float*)d_in[0];
  const float* w1 = (const float*)d_in[1];
  const float* b1 = (const float*)d_in[2];
  const float* w2 = (const float*)d_in[3];
  const float* b2 = (const float*)d_in[4];
  const float* qw = (const float*)d_in[5];
  const float* qb = (const float*)d_in[6];
  const float* kw = (const float*)d_in[7];
  const float* kb = (const float*)d_in[8];
  const float* vw = (const float*)d_in[9];
  const float* vb = (const float*)d_in[10];
  float* out = (float*)d_out;

  char* ws = (char*)d_ws;
  const size_t MB = 1024 * 1024;
  unsigned short* x_bf  = (unsigned short*)(ws);             // 8 MB
  unsigned short* h_bf  = (unsigned short*)(ws + 8  * MB);   // 8 MB
  unsigned short* m_bf  = (unsigned short*)(ws + 16 * MB);   // 8 MB
  unsigned short* qkbuf = (unsigned short*)(ws + 24 * MB);   // 16 MB [4096][2048]
  unsigned short* vtbuf = (unsigned short*)(ws + 40 * MB);   // 8 MB  [1024][4096]
  unsigned short* w1t   = (unsigned short*)(ws + 48 * MB);   // 2 MB
  unsigned short* w2t   = (unsigned short*)(ws + 50 * MB);   // 2 MB
  unsigned short* wqkvt = (unsigned short*)(ws + 52 * MB);   // 6 MB

  cvt_kernel<<<NELEM_ACT / (256 * 8), 256, 0, stream>>>(x, x_bf, NELEM_ACT);
  transpose5_kernel<<<dim3(32, 32, 5), 256, 0, stream>>>(w1, w2, qw, kw, vw,
                                                         w1t, w2t, wqkvt);

  // MLP GEMMs: 64x128 tile -> 512 blocks, LDS 2x24KB, NL=6
  dim3 g1(DIMN / 128, MTOT / 64);
  gemm_kernel<2, 4, 0><<<g1, 256, 0, stream>>>(x_bf, w1t, b1, nullptr, nullptr,
                                               h_bf, nullptr, DIMN, DIMN);
  gemm_kernel<2, 4, 1><<<g1, 256, 0, stream>>>(h_bf, w2t, b2, nullptr, nullptr,
                                               m_bf, nullptr, DIMN, DIMN);
  // fused QKV GEMM: 128x128 tile over N=3072 -> 768 blocks, LDS 2x32KB, NL=8
  dim3 g2(3 * DIMN / 128, MTOT / 128);
  gemm_kernel<4, 4, 2><<<g2, 256, 0, stream>>>(m_bf, wqkvt, qb, kb, vb,
                                               qkbuf, vtbuf, 3 * DIMN, DIMN);

  attn_mfma_kernel<<<MTOT / QBLK, 256, 0, stream>>>(qkbuf, vtbuf, out);
}

// Round 9
// 228.708 us; speedup vs baseline: 2.7296x; 1.0019x over previous
//
#include <hip/hip_runtime.h>
#include <cstdint>

#define DIMN 1024
#define SEQ  2048
#define BATCH 2
#define MTOT (BATCH*SEQ)      // 4096 rows
#define NELEM_ACT (MTOT*DIMN) // 4,194,304
#define NELEM_W   (DIMN*DIMN) // 1,048,576

typedef __attribute__((ext_vector_type(8))) short   s16x8;
typedef __attribute__((ext_vector_type(4))) float   f32x4v;

__device__ __forceinline__ float b2f(unsigned short u) {
  union { unsigned int i; float f; } x; x.i = ((unsigned int)u) << 16; return x.f;
}
__device__ __forceinline__ unsigned short f2b(float f) {
  unsigned int x = __float_as_uint(f);
  return (unsigned short)((x + 0x7fffu + ((x >> 16) & 1u)) >> 16);
}

__device__ __forceinline__ void gload16(const void* g, void* l) {
  __builtin_amdgcn_global_load_lds((const __attribute__((address_space(1))) void*)g,
                                   (__attribute__((address_space(3))) void*)l,
                                   16, 0, 0);
}

// counted vmcnt wait, literal immediates (T4)
template<int N> __device__ __forceinline__ void waitvm() {
  if constexpr (N == 0)       asm volatile("s_waitcnt vmcnt(0)" ::: "memory");
  else if constexpr (N == 3)  asm volatile("s_waitcnt vmcnt(3)" ::: "memory");
  else if constexpr (N == 4)  asm volatile("s_waitcnt vmcnt(4)" ::: "memory");
  else if constexpr (N == 6)  asm volatile("s_waitcnt vmcnt(6)" ::: "memory");
  else if constexpr (N == 8)  asm volatile("s_waitcnt vmcnt(8)" ::: "memory");
  else if constexpr (N == 9)  asm volatile("s_waitcnt vmcnt(9)" ::: "memory");
  else if constexpr (N == 12) asm volatile("s_waitcnt vmcnt(12)" ::: "memory");
  else static_assert(N == 0, "add a case");
}

// ---------------------------------------------------------------------------
// fp32 -> bf16 (elementwise, 8 elems/thread)
// ---------------------------------------------------------------------------
__global__ __launch_bounds__(256) void cvt_kernel(
    const float* __restrict__ in, unsigned short* __restrict__ out, int n) {
  int i = (blockIdx.x * 256 + threadIdx.x) * 8;
  if (i >= n) return;
  float4 v0 = *(const float4*)(in + i);
  float4 v1 = *(const float4*)(in + i + 4);
  ushort4 a, b;
  a.x = f2b(v0.x); a.y = f2b(v0.y); a.z = f2b(v0.z); a.w = f2b(v0.w);
  b.x = f2b(v1.x); b.y = f2b(v1.y); b.z = f2b(v1.z); b.w = f2b(v1.w);
  *(ushort4*)(out + i) = a;
  *(ushort4*)(out + i + 4) = b;
}

// ---------------------------------------------------------------------------
// All 5 weight transposes in one dispatch; z selects the weight.
// ---------------------------------------------------------------------------
__global__ __launch_bounds__(256) void transpose5_kernel(
    const float* __restrict__ w1, const float* __restrict__ w2,
    const float* __restrict__ qw, const float* __restrict__ kw,
    const float* __restrict__ vw,
    unsigned short* __restrict__ w1t, unsigned short* __restrict__ w2t,
    unsigned short* __restrict__ wqkvt) {
  __shared__ float t[32][33];
  int z = blockIdx.z;
  const float* in = (z == 0) ? w1 : (z == 1) ? w2 : (z == 2) ? qw : (z == 3) ? kw : vw;
  unsigned short* dst = (z == 0) ? w1t : (z == 1) ? w2t : wqkvt + (size_t)(z - 2) * NELEM_W;

  int tx = threadIdx.x & 31, ty = threadIdx.x >> 5;  // 32 x 8
  int r0 = blockIdx.y * 32, c0 = blockIdx.x * 32;
  #pragma unroll
  for (int i = 0; i < 32; i += 8)
    t[ty + i][tx] = in[(size_t)(r0 + ty + i) * DIMN + c0 + tx];
  __syncthreads();
  #pragma unroll
  for (int i = 0; i < 32; i += 8)
    dst[(size_t)(c0 + ty + i) * DIMN + r0 + tx] = f2b(t[tx][ty + i]);
}

// ---------------------------------------------------------------------------
// GEMM: C[M,N] = A[M,K] @ Bt[N,K]^T + bias   (bf16 in, f32 accum)
// Block tile (MF*32) x (NF*32), BK=32, 256 threads = 4 waves as 2x2.
// LOOKAHEAD-3 RING (T4): 4 static LDS buffers, raw s_barrier + counted
//   s_waitcnt vmcnt(k*NL) so up to 3 K-tiles of loads stay in flight across
//   barriers (lookahead ~3 phases ~ covers L2/L3-miss latency, m218 lever).
//   Per step s: waitvm(min(3,nt-1-s)*NL) -> barrier -> sched_barrier ->
//   compute(buf s%4) -> barrier -> stage(buf s%4, s+4).
//   Static x4 unroll keeps buffer pointers compile-time (rule 20).
// No XCD swizzle (r8 post-mortem: contiguous-chunk swizzle thrashed B per
//   XCD L2, FETCH 40->58MB; natural round-robin keeps B-columns resident).
// Fragment-major LDS (1KB 16x32 blocks): gload16 + ds_read_b128 conflict-free.
// EPI 0: relu+bf16.  EPI 1: bf16.
// EPI 2 (fused QKV, N=3072): cols 0..2047 -> qk[token][2048] (q|k);
//        cols 2048.. -> VT[d][token] transposed write, bias per group.
// Requires Kdim % 128 == 0.
// ---------------------------------------------------------------------------
template<int MF, int NF, int EPI>
__global__ __launch_bounds__(256) void gemm_kernel(
    const unsigned short* __restrict__ A, const unsigned short* __restrict__ Bt,
    const float* __restrict__ bias0, const float* __restrict__ bias1,
    const float* __restrict__ bias2,
    unsigned short* __restrict__ O, unsigned short* __restrict__ O2,
    int Ndim, int Kdim) {
  constexpr int TB = (MF + NF) * 2;              // 1KB blocks per buffer (BK=32)
  constexpr int NL = TB / 4;                     // per-thread loads per stage
  __shared__ unsigned short lds[4 * TB * 512];

  const int tid  = threadIdx.x;
  const int lane = tid & 63;
  const int wave = tid >> 6;
  const int wm = wave >> 1;
  const int wn = wave & 1;
  const int frow = lane & 15;
  const int krow = lane >> 4;
  const int bm0 = blockIdx.y * (MF * 32);
  const int bn0 = blockIdx.x * (NF * 32);

  f32x4v acc[MF][NF] = {};

  auto stage = [&](unsigned short* dst, int k0) {
    #pragma unroll
    for (int t = 0; t < NL; ++t) {
      int i = wave + t * 4;
      const unsigned short* src;
      if (i < MF * 2) {
        src = A + (size_t)(bm0 + i * 16 + frow) * Kdim + k0 + krow * 8;
      } else {
        int j = i - MF * 2;
        src = Bt + (size_t)(bn0 + j * 16 + frow) * Kdim + k0 + krow * 8;
      }
      gload16(src, dst + i * 512);
    }
  };

  auto compute = [&](const unsigned short* buf) {
    const short* sl = (const short*)buf;
    s16x8 a[MF], b[NF];
    #pragma unroll
    for (int m = 0; m < MF; ++m)
      a[m] = *(const s16x8*)(sl + (wm * MF + m) * 512 + lane * 8);
    #pragma unroll
    for (int n = 0; n < NF; ++n)
      b[n] = *(const s16x8*)(sl + (MF * 2 + wn * NF + n) * 512 + lane * 8);
    #pragma unroll
    for (int m = 0; m < MF; ++m)
      #pragma unroll
      for (int n = 0; n < NF; ++n)
        acc[m][n] = __builtin_amdgcn_mfma_f32_16x16x32_bf16(a[m], b[n], acc[m][n], 0, 0, 0);
  };

  const int nt = Kdim >> 5;        // BK=32 steps; Kdim=1024 -> 32 (mult of 4)
  unsigned short* b0 = lds;
  unsigned short* b1 = lds + TB * 512;
  unsigned short* b2 = lds + 2 * TB * 512;
  unsigned short* b3 = lds + 3 * TB * 512;

  stage(b0, 0); stage(b1, 32); stage(b2, 64); stage(b3, 96);

  for (int t = 0; t < nt; t += 4) {
    #define PHASE(P, BUF)                                                     \
    {                                                                         \
      int s = t + P;                                                          \
      int rem = nt - 1 - s;          /* uniform */                            \
      if (rem >= 3)      waitvm<3 * NL>();                                    \
      else if (rem == 2) waitvm<2 * NL>();                                    \
      else if (rem == 1) waitvm<NL>();                                        \
      else               waitvm<0>();                                         \
      __builtin_amdgcn_s_barrier();                                           \
      __builtin_amdgcn_sched_barrier(0);                                      \
      compute(BUF);                                                           \
      __builtin_amdgcn_s_barrier();                                           \
      if (s + 4 < nt) stage(BUF, (s + 4) << 5);                               \
    }
    PHASE(0, b0)
    PHASE(1, b1)
    PHASE(2, b2)
    PHASE(3, b3)
    #undef PHASE
  }

  // epilogue: frag C row = (lane>>4)*4 + r, col = lane&15
  #pragma unroll
  for (int n = 0; n < NF; ++n) {
    int col = bn0 + wn * (NF * 16) + n * 16 + frow;
    float bv;
    if (EPI == 2) {
      int sel = col >> 10;
      const float* bp = (sel == 0) ? bias0 : (sel == 1) ? bias1 : bias2;
      bv = bp[col & (DIMN - 1)];
    } else {
      bv = bias0[col];
    }
    #pragma unroll
    for (int m = 0; m < MF; ++m) {
      int rbase = bm0 + wm * (MF * 16) + m * 16 + krow * 4;
      if (EPI == 2 && col >= 2048) {
        // transposed V write: VT[d][token], 4 consecutive tokens -> 8B store
        int d = col - 2048;
        ushort4 pk;
        pk.x = f2b(acc[m][n][0] + bv); pk.y = f2b(acc[m][n][1] + bv);
        pk.z = f2b(acc[m][n][2] + bv); pk.w = f2b(acc[m][n][3] + bv);
        *(ushort4*)(O2 + (size_t)d * MTOT + rbase) = pk;
      } else {
        #pragma unroll
        for (int r = 0; r < 4; ++r) {
          float v = acc[m][n][r] + bv;
          if (EPI == 0) v = fmaxf(v, 0.f);
          if (EPI == 2) O[(size_t)(rbase + r) * 2048 + col] = f2b(v);
          else          O[(size_t)(rbase + r) * Ndim + col] = f2b(v);
        }
      }
    }
  }
}

// ---------------------------------------------------------------------------
// MFMA sliding-window attention.  One block per 32 queries (grid 128).
// Padded key window: 96 keys [s0-32, s0+63].  4 waves: qf = w&1 (16 q rows),
// kh = w>>1 (key half for QK / d half for PV).
// S^T = K @ Q^T so softmax is lane-local per q (4-lane shfl groups) with a
// 2-half LDS combine.  P -> bf16 in padded LDS.  PV uses VT[d][token].
// (unchanged for attribution)
// ---------------------------------------------------------------------------
#define QBLK 32
#define NEGI (-1.0e30f)

__global__ __launch_bounds__(256) void attn_mfma_kernel(
    const unsigned short* __restrict__ qk,   // [MTOT][2048]  (q|k)
    const unsigned short* __restrict__ vt,   // [DIMN][MTOT]
    float* __restrict__ out) {               // [MTOT][DIMN]
  __shared__ unsigned short stage[24 * 512];   // 24 KB
  __shared__ unsigned short plds[QBLK][136];   // P bf16, padded
  __shared__ float pmax[2][QBLK];
  __shared__ float psum[2][QBLK];

  const int tid = threadIdx.x, lane = tid & 63, wave = tid >> 6;
  const int frow = lane & 15, krow = lane >> 4;
  const int tok0 = blockIdx.x * QBLK;
  const int s0 = tok0 & (SEQ - 1);
  const int bbase = tok0 - s0;
  const int qf = wave & 1;
  const int kh = wave >> 1;

  // ---------------- QK^T ----------------
  f32x4v sacc[3] = {};
  for (int d0 = 0; d0 < DIMN; d0 += 64) {
    #pragma unroll
    for (int t = 0; t < 4; ++t) {
      int i = wave + t * 4;
      const unsigned short* src;
      if (i < 4) {
        int qfs = i >> 1, ds = i & 1;
        src = qk + (size_t)(tok0 + qfs * 16 + frow) * 2048 + d0 + ds * 32 + krow * 8;
      } else {
        int j = i - 4;
        int kf = j >> 1, ds = j & 1;
        int kpos = s0 - 32 + kf * 16 + frow;
        kpos = min(max(kpos, 0), SEQ - 1);
        src = qk + (size_t)(bbase + kpos) * 2048 + 1024 + d0 + ds * 32 + krow * 8;
      }
      gload16(src, stage + i * 512);
    }
    __syncthreads();
    const short* sl = (const short*)stage;
    #pragma unroll
    for (int ds = 0; ds < 2; ++ds) {
      s16x8 bq = *(const s16x8*)(sl + (qf * 2 + ds) * 512 + lane * 8);
      #pragma unroll
      for (int f = 0; f < 3; ++f) {
        int kf = kh * 3 + f;
        s16x8 ak = *(const s16x8*)(sl + (4 + kf * 2 + ds) * 512 + lane * 8);
        sacc[f] = __builtin_amdgcn_mfma_f32_16x16x32_bf16(ak, bq, sacc[f], 0, 0, 0);
      }
    }
    __syncthreads();
  }

  // ---------------- mask + softmax ----------------
  const int qloc = qf * 16 + frow;
  const int qpos = s0 + qloc;
  float sv[3][4];
  float mx = NEGI;
  #pragma unroll
  for (int f = 0; f < 3; ++f) {
    #pragma unroll
    for (int r = 0; r < 4; ++r) {
      int kloc = (kh * 3 + f) * 16 + krow * 4 + r;
      int kpos = s0 - 32 + kloc;
      int dd = kpos - qpos;
      bool valid = (dd >= -32) && (dd <= 32) && (kpos >= 0) && (kpos < SEQ);
      float v = valid ? sacc[f][r] * 0.03125f : NEGI;
      sv[f][r] = v;
      mx = fmaxf(mx, v);
    }
  }
  mx = fmaxf(mx, __shfl_xor(mx, 16));
  mx = fmaxf(mx, __shfl_xor(mx, 32));
  if (lane < 16) pmax[kh][qf * 16 + lane] = mx;
  __syncthreads();
  float M = fmaxf(pmax[0][qloc], pmax[1][qloc]);
  float sum = 0.f;
  unsigned int pw[3][2];
  #pragma unroll
  for (int f = 0; f < 3; ++f) {
    #pragma unroll
    for (int pr = 0; pr < 2; ++pr) {
      float p0 = __expf(sv[f][2 * pr]     - M);
      float p1 = __expf(sv[f][2 * pr + 1] - M);
      sum += p0 + p1;
      pw[f][pr] = (unsigned int)f2b(p0) | ((unsigned int)f2b(p1) << 16);
    }
  }
  sum += __shfl_xor(sum, 16);
  sum += __shfl_xor(sum, 32);
  if (lane < 16) psum[kh][qf * 16 + lane] = sum;
  {
    unsigned int* pl = (unsigned int*)&plds[0][0];
    int base = qloc * 68 + (kh * 3) * 8 + krow * 2;
    #pragma unroll
    for (int f = 0; f < 3; ++f) {
      pl[base + f * 8 + 0] = pw[f][0];
      pl[base + f * 8 + 1] = pw[f][1];
    }
  }
  __syncthreads();

  // ---------------- PV ----------------
  s16x8 pa[3];
  #pragma unroll
  for (int kf = 0; kf < 3; ++kf)
    pa[kf] = *(const s16x8*)((const short*)&plds[0][0] +
                             (qf * 16 + frow) * 136 + kf * 32 + krow * 8);
  float rden[4];
  #pragma unroll
  for (int r = 0; r < 4; ++r) {
    int q = qf * 16 + krow * 4 + r;
    rden[r] = 1.f / (psum[0][q] + psum[1][q]);
  }

  for (int c = 0; c < 8; ++c) {           // d-chunks of 128
    #pragma unroll
    for (int t = 0; t < 6; ++t) {
      int i = wave + t * 4;
      int kf = i >> 3, nf = i & 7;
      int d = c * 128 + nf * 16 + frow;
      int tt = s0 - 32 + kf * 32 + krow * 8;
      tt = min(max(tt, 0), SEQ - 8);      // 8-token groups never straddle
      gload16(vt + (size_t)d * MTOT + bbase + tt, stage + i * 512);
    }
    __syncthreads();
    const short* sl = (const short*)stage;
    f32x4v oacc[4] = {};
    #pragma unroll
    for (int kf = 0; kf < 3; ++kf) {
      #pragma unroll
      for (int n = 0; n < 4; ++n) {
        int nf = kh * 4 + n;
        s16x8 bv = *(const s16x8*)(sl + (kf * 8 + nf) * 512 + lane * 8);
        oacc[n] = __builtin_amdgcn_mfma_f32_16x16x32_bf16(pa[kf], bv, oacc[n], 0, 0, 0);
      }
    }
    #pragma unroll
    for (int n = 0; n < 4; ++n) {
      int d = c * 128 + (kh * 4 + n) * 16 + frow;
      #pragma unroll
      for (int r = 0; r < 4; ++r) {
        int q = qf * 16 + krow * 4 + r;
        out[(size_t)(tok0 + q) * DIMN + d] = oacc[n][r] * rden[r];
      }
    }
    __syncthreads();
  }
}

// ---------------------------------------------------------------------------
extern "C" void kernel_launch(void* const* d_in, const int* in_sizes, int n_in,
                              void* d_out, int out_size, void* d_ws, size_t ws_size,
                              hipStream_t stream) {
  const float* x  = (const float*)d_in[0];
  const float* w1 = (const float*)d_in[1];
  const float* b1 = (const float*)d_in[2];
  const float* w2 = (const float*)d_in[3];
  const float* b2 = (const float*)d_in[4];
  const float* qw = (const float*)d_in[5];
  const float* qb = (const float*)d_in[6];
  const float* kw = (const float*)d_in[7];
  const float* kb = (const float*)d_in[8];
  const float* vw = (const float*)d_in[9];
  const float* vb = (const float*)d_in[10];
  float* out = (float*)d_out;

  char* ws = (char*)d_ws;
  const size_t MB = 1024 * 1024;
  unsigned short* x_bf  = (unsigned short*)(ws);             // 8 MB
  unsigned short* h_bf  = (unsigned short*)(ws + 8  * MB);   // 8 MB
  unsigned short* m_bf  = (unsigned short*)(ws + 16 * MB);   // 8 MB
  unsigned short* qkbuf = (unsigned short*)(ws + 24 * MB);   // 16 MB [4096][2048]
  unsigned short* vtbuf = (unsigned short*)(ws + 40 * MB);   // 8 MB  [1024][4096]
  unsigned short* w1t   = (unsigned short*)(ws + 48 * MB);   // 2 MB
  unsigned short* w2t   = (unsigned short*)(ws + 50 * MB);   // 2 MB
  unsigned short* wqkvt = (unsigned short*)(ws + 52 * MB);   // 6 MB

  cvt_kernel<<<NELEM_ACT / (256 * 8), 256, 0, stream>>>(x, x_bf, NELEM_ACT);
  transpose5_kernel<<<dim3(32, 32, 5), 256, 0, stream>>>(w1, w2, qw, kw, vw,
                                                         w1t, w2t, wqkvt);

  // MLP GEMMs: 64x128 tile -> 512 blocks, 4x12KB LDS ring, NL=3
  dim3 g1(DIMN / 128, MTOT / 64);
  gemm_kernel<2, 4, 0><<<g1, 256, 0, stream>>>(x_bf, w1t, b1, nullptr, nullptr,
                                               h_bf, nullptr, DIMN, DIMN);
  gemm_kernel<2, 4, 1><<<g1, 256, 0, stream>>>(h_bf, w2t, b2, nullptr, nullptr,
                                               m_bf, nullptr, DIMN, DIMN);
  // fused QKV GEMM: 128x128 tile over N=3072 -> 768 blocks, 4x16KB ring, NL=4
  dim3 g2(3 * DIMN / 128, MTOT / 128);
  gemm_kernel<4, 4, 2><<<g2, 256, 0, stream>>>(m_bf, wqkvt, qb, kb, vb,
                                               qkbuf, vtbuf, 3 * DIMN, DIMN);

  attn_mfma_kernel<<<MTOT / QBLK, 256, 0, stream>>>(qkbuf, vtbuf, out);
}